// Round 1
// baseline (4063.012 us; speedup 1.0000x reference)
//
#include <hip/hip_runtime.h>
#include <hip/hip_bf16.h>

// ---------------- problem constants ----------------
#define CEMB 256
#define NHEAD 8
#define DHEAD 32
#define DFF 1024
#define BB 4
#define HH 128
#define WW 128
#define WSZ 16
#define NWH 8
#define NW 64
#define TT 256            // tokens per window
#define NTOK (BB*NW*TT)   // 65536

// bf16 helpers (storage type = ushort)
__device__ __forceinline__ float bf2f(unsigned short u){
    union { float f; unsigned int i; } v; v.i = ((unsigned int)u) << 16; return v.f;
}
__device__ __forceinline__ unsigned short f2bf(float f){
    union { float f; unsigned int i; } v; v.f = f;
    unsigned int r = v.i + 0x7fffu + ((v.i >> 16) & 1u);
    return (unsigned short)(r >> 16);
}
__device__ __forceinline__ void unpack8(uint4 v, float* f){
    f[0]=bf2f((unsigned short)(v.x & 0xffff)); f[1]=bf2f((unsigned short)(v.x>>16));
    f[2]=bf2f((unsigned short)(v.y & 0xffff)); f[3]=bf2f((unsigned short)(v.y>>16));
    f[4]=bf2f((unsigned short)(v.z & 0xffff)); f[5]=bf2f((unsigned short)(v.z>>16));
    f[6]=bf2f((unsigned short)(v.w & 0xffff)); f[7]=bf2f((unsigned short)(v.w>>16));
}

// ---------------- K1: rel-MLP + pos = gp + rel  ->  pos[nw][T][C] bf16 ----------------
__global__ __launch_bounds__(256) void pos_kernel(const float* __restrict__ gp,
    const float* __restrict__ rw1, const float* __restrict__ rb1,
    const float* __restrict__ rw2, const float* __restrict__ rb2,
    unsigned short* __restrict__ pos)
{
    int wt = blockIdx.x;              // 0..NW*TT-1
    int w = wt >> 8, t = wt & 255;
    int c = threadIdx.x;
    int ty = t >> 4, tx = t & 15;
    float y = ty * (1.0f/15.0f), x = tx * (1.0f/15.0f);
    float acc = rb2[c];
    #pragma unroll 8
    for (int k = 0; k < 64; ++k){
        float h = fmaxf(y*rw1[2*k] + x*rw1[2*k+1] + rb1[k], 0.0f);
        acc += h * rw2[c*64 + k];
    }
    int wh = w >> 3, wwi = w & 7;
    float g = gp[(size_t)c*(HH*WW) + (wh*16 + ty)*WW + wwi*16 + tx];
    pos[(size_t)wt*CEMB + c] = f2bf(g + acc);
}

// ---------------- K2: window validity (max-pool > 0) ----------------
__global__ __launch_bounds__(256) void valid_kernel(const float* __restrict__ defe,
    float* __restrict__ validf, float* __restrict__ tail)
{
    __shared__ float red[4];
    int bw = blockIdx.x; int b = bw >> 6, w = bw & 63;
    int t = threadIdx.x; int ty = t >> 4, tx = t & 15;
    int wh = w >> 3, wwi = w & 7;
    float v = defe[(size_t)b*(HH*WW) + (wh*16+ty)*WW + wwi*16 + tx];
    int lane = t & 63, wave = t >> 6;
    for (int off = 1; off < 64; off <<= 1) v = fmaxf(v, __shfl_xor(v, off));
    if (lane == 0) red[wave] = v;
    __syncthreads();
    if (t == 0){
        float m = fmaxf(fmaxf(red[0], red[1]), fmaxf(red[2], red[3]));
        float r = (m > 0.0f) ? 1.0f : 0.0f;
        validf[bw] = r;
        tail[bw] = r;
    }
}

// ---------------- K3: window partition  backbone[B,C,H,W] -> x[b,w,t,c] bf16 ----------------
__global__ __launch_bounds__(256) void partition_kernel(const float* __restrict__ bb,
    unsigned short* __restrict__ x)
{
    __shared__ float tile[64][257];
    int bw = blockIdx.x; int b = bw >> 6, w = bw & 63;
    int wh = w >> 3, wwi = w & 7;
    int tid = threadIdx.x;
    const float* bbb = bb + (size_t)b*CEMB*HH*WW + (size_t)(wh*16)*WW + wwi*16;
    for (int c0 = 0; c0 < 256; c0 += 64){
        for (int i = 0; i < 64; ++i){
            int e = i*256 + tid; int c = e >> 8, t = e & 255;
            tile[c][t] = bbb[(size_t)(c0 + c)*(HH*WW) + (t >> 4)*WW + (t & 15)];
        }
        __syncthreads();
        for (int i = 0; i < 64; ++i){
            int e = i*256 + tid; int t = e >> 6, cc = e & 63;
            x[((size_t)bw*256 + t)*CEMB + c0 + cc] = f2bf(tile[cc][t]);
        }
        __syncthreads();
    }
}

// ---------------- generic GEMM: out[M,N](bf16) = A[M,K](bf16 [+pos]) @ W[N,K]^T + bias ----------------
// 128x128 tile, BK=16, 256 threads, 8x8 per thread (split 4+4 for conflict-free LDS reads)
__global__ __launch_bounds__(256) void gemm_kernel(
    const unsigned short* __restrict__ A, int ldA,
    const unsigned short* __restrict__ pos, int posNlimit,
    const float* __restrict__ W, int K, const float* __restrict__ bias,
    unsigned short* __restrict__ out, int ldO, int relu)
{
    __shared__ float As[16][132];
    __shared__ float Bs[16][132];
    const int m0 = blockIdx.x << 7;
    const int n0 = blockIdx.y << 7;
    const int tid = threadIdx.x;
    const int lr = tid >> 1;            // 0..127 (tile row)
    const int lk = (tid & 1) << 3;      // 0 or 8
    const int tx = tid & 15, ty = tid >> 4;
    const bool usePos = (pos != nullptr) && (n0 < posNlimit);
    float acc[8][8];
    #pragma unroll
    for (int i = 0; i < 8; ++i)
        #pragma unroll
        for (int j = 0; j < 8; ++j) acc[i][j] = 0.0f;

    const unsigned short* aRow = A + (size_t)(m0 + lr)*ldA + lk;
    const float*          wRow = W + (size_t)(n0 + lr)*K + lk;
    const unsigned short* pRow = usePos ? (pos + (size_t)((m0 + lr) & 16383)*CEMB + lk) : nullptr;

    for (int k0 = 0; k0 < K; k0 += 16){
        uint4 avv = *(const uint4*)(aRow + k0);
        float af[8]; unpack8(avv, af);
        if (usePos){
            uint4 pv = *(const uint4*)(pRow + k0);
            float pf[8]; unpack8(pv, pf);
            #pragma unroll
            for (int j = 0; j < 8; ++j) af[j] += pf[j];
        }
        float4 w0 = *(const float4*)(wRow + k0);
        float4 w1 = *(const float4*)(wRow + k0 + 4);
        #pragma unroll
        for (int j = 0; j < 8; ++j) As[lk + j][lr] = af[j];
        Bs[lk+0][lr] = w0.x; Bs[lk+1][lr] = w0.y; Bs[lk+2][lr] = w0.z; Bs[lk+3][lr] = w0.w;
        Bs[lk+4][lr] = w1.x; Bs[lk+5][lr] = w1.y; Bs[lk+6][lr] = w1.z; Bs[lk+7][lr] = w1.w;
        __syncthreads();
        #pragma unroll
        for (int kk = 0; kk < 16; ++kk){
            float4 a0 = *(const float4*)&As[kk][tx << 2];
            float4 a1 = *(const float4*)&As[kk][64 + (tx << 2)];
            float4 b0 = *(const float4*)&Bs[kk][ty << 2];
            float4 b1 = *(const float4*)&Bs[kk][64 + (ty << 2)];
            float av[8] = {a0.x,a0.y,a0.z,a0.w,a1.x,a1.y,a1.z,a1.w};
            float bv[8] = {b0.x,b0.y,b0.z,b0.w,b1.x,b1.y,b1.z,b1.w};
            #pragma unroll
            for (int i = 0; i < 8; ++i)
                #pragma unroll
                for (int j = 0; j < 8; ++j) acc[i][j] += av[i]*bv[j];
        }
        __syncthreads();
    }
    float bj[8];
    #pragma unroll
    for (int j = 0; j < 4; ++j){
        bj[j]   = bias[n0 + (ty<<2) + j];
        bj[4+j] = bias[n0 + 64 + (ty<<2) + j];
    }
    #pragma unroll
    for (int i = 0; i < 8; ++i){
        int m = m0 + ((i < 4) ? ((tx<<2) + i) : (64 + (tx<<2) + (i-4)));
        float o[8];
        #pragma unroll
        for (int j = 0; j < 8; ++j){
            o[j] = acc[i][j] + bj[j];
            if (relu) o[j] = fmaxf(o[j], 0.0f);
        }
        ushort4 lo, hi;
        lo.x = f2bf(o[0]); lo.y = f2bf(o[1]); lo.z = f2bf(o[2]); lo.w = f2bf(o[3]);
        hi.x = f2bf(o[4]); hi.y = f2bf(o[5]); hi.z = f2bf(o[6]); hi.w = f2bf(o[7]);
        *(ushort4*)&out[(size_t)m*ldO + n0 + (ty<<2)]      = lo;
        *(ushort4*)&out[(size_t)m*ldO + n0 + 64 + (ty<<2)] = hi;
    }
}

// ---------------- attention: block per (seq, head); fp32 LDS GEMM-structured ----------------
// layer0: L=256, stride=1 token (within-window).  layer1: L=64, stride=256 tokens (cross-window, masked)
template<int L, bool CROSS>
__global__ __launch_bounds__(256) void attn_kernel(const unsigned short* __restrict__ qkv,
    unsigned short* __restrict__ attn_out, const float* __restrict__ validf)
{
    __shared__ float Kt[32][L + 8];      // [d][j]
    __shared__ float Vs[L][36];          // [j][d]
    __shared__ float Qt[32][72];         // [d][q] (q-tile of 64)
    __shared__ float St[L][68];          // [j][q]
    __shared__ float lsum[64];
    __shared__ float vmask[CROSS ? L : 1];

    const int s = blockIdx.x, h = blockIdx.y;
    int base, stride;
    if (CROSS){ int b = s >> 8; base = b*16384 + (s & 255); stride = 256; }
    else      { base = s << 8; stride = 1; }
    const int tid = threadIdx.x;
    const int wave = tid >> 6, lane = tid & 63;
    const float scale = 0.17677669529663687f;

    for (int e = tid; e < L*32; e += 256){
        int j = e >> 5, d = e & 31;
        size_t tok = (size_t)(base + j*stride);
        Kt[d][j] = bf2f(qkv[tok*768 + 256 + h*32 + d]);
        Vs[j][d] = bf2f(qkv[tok*768 + 512 + h*32 + d]);
    }
    if (CROSS){
        for (int e = tid; e < L; e += 256) vmask[e] = validf[(s >> 8)*64 + e];
    }
    __syncthreads();

    for (int q0 = 0; q0 < L; q0 += 64){
        for (int e = tid; e < 64*32; e += 256){
            int q = e >> 5, d = e & 31;
            size_t tok = (size_t)(base + (q0 + q)*stride);
            Qt[d][q] = bf2f(qkv[tok*768 + h*32 + d]);
        }
        __syncthreads();
        // phase A: St[j][q] = scale * sum_d K[j][d] Q[q][d]  (32x32 wave tiles)
        {
            const int jg = lane & 7, qg = lane >> 3;
            const int nTiles = (L/32) * 2;
            for (int tile = wave; tile < nTiles; tile += 4){
                int tj = (tile >> 1) << 5;
                int tq = (tile & 1) << 5;
                float a[4][4] = {{0.0f}};
                #pragma unroll
                for (int d = 0; d < 32; ++d){
                    float4 kv = *(const float4*)&Kt[d][tj + (jg<<2)];
                    float4 qv = *(const float4*)&Qt[d][tq + (qg<<2)];
                    a[0][0] += kv.x*qv.x; a[0][1] += kv.x*qv.y; a[0][2] += kv.x*qv.z; a[0][3] += kv.x*qv.w;
                    a[1][0] += kv.y*qv.x; a[1][1] += kv.y*qv.y; a[1][2] += kv.y*qv.z; a[1][3] += kv.y*qv.w;
                    a[2][0] += kv.z*qv.x; a[2][1] += kv.z*qv.y; a[2][2] += kv.z*qv.z; a[2][3] += kv.z*qv.w;
                    a[3][0] += kv.w*qv.x; a[3][1] += kv.w*qv.y; a[3][2] += kv.w*qv.z; a[3][3] += kv.w*qv.w;
                }
                #pragma unroll
                for (int jj = 0; jj < 4; ++jj){
                    int j = tj + (jg<<2) + jj;
                    float4 sv = make_float4(a[jj][0]*scale, a[jj][1]*scale, a[jj][2]*scale, a[jj][3]*scale);
                    if (CROSS && vmask[j] == 0.0f){ sv.x = sv.y = sv.z = sv.w = -3.0e38f; }
                    *(float4*)&St[j][tq + (qg<<2)] = sv;
                }
            }
        }
        __syncthreads();
        // softmax over j for each query column (wave: 16 q, 4 segments per q)
        {
            const int q = wave*16 + (lane & 15);
            const int seg = lane >> 4;
            float m = -3.4e38f;
            for (int j = seg; j < L; j += 4) m = fmaxf(m, St[j][q]);
            m = fmaxf(m, __shfl_xor(m, 16));
            m = fmaxf(m, __shfl_xor(m, 32));
            float l = 0.0f;
            for (int j = seg; j < L; j += 4){
                float p = __expf(St[j][q] - m);
                St[j][q] = p;
                l += p;
            }
            l += __shfl_xor(l, 16);
            l += __shfl_xor(l, 32);
            if (seg == 0) lsum[q] = l;
        }
        __syncthreads();
        // phase B: O[q][d] = sum_j P[j][q] * V[j][d]; wave: 16 q, lane = (qpair, dgroup)
        {
            const int dg = lane & 7;
            const int qb = wave*16 + ((lane >> 3) & 7)*2;
            float acc0[4] = {0,0,0,0}, acc1[4] = {0,0,0,0};
            #pragma unroll 8
            for (int j = 0; j < L; ++j){
                float2 p = *(const float2*)&St[j][qb];
                float4 v = *(const float4*)&Vs[j][dg<<2];
                acc0[0] += p.x*v.x; acc0[1] += p.x*v.y; acc0[2] += p.x*v.z; acc0[3] += p.x*v.w;
                acc1[0] += p.y*v.x; acc1[1] += p.y*v.y; acc1[2] += p.y*v.z; acc1[3] += p.y*v.w;
            }
            #pragma unroll
            for (int qq = 0; qq < 2; ++qq){
                int q = qb + qq;
                float rl = 1.0f / lsum[q];
                size_t tok = (size_t)(base + (q0 + q)*stride);
                const float* ac = qq ? acc1 : acc0;
                ushort4 st;
                st.x = f2bf(ac[0]*rl); st.y = f2bf(ac[1]*rl);
                st.z = f2bf(ac[2]*rl); st.w = f2bf(ac[3]*rl);
                *(ushort4*)&attn_out[tok*CEMB + h*32 + (dg<<2)] = st;
            }
        }
        __syncthreads();
    }
}

// ---------------- layernorm: out = LN(sin + resid) * g + b  (token per wave) ----------------
__global__ __launch_bounds__(256) void ln_kernel(const unsigned short* __restrict__ sin_,
    const unsigned short* __restrict__ resid, const float* __restrict__ g,
    const float* __restrict__ b, unsigned short* __restrict__ out)
{
    int tid = threadIdx.x;
    int wave = tid >> 6, lane = tid & 63;
    size_t token = (size_t)blockIdx.x*4 + wave;
    ushort4 sv = *(const ushort4*)&sin_[token*CEMB + (lane<<2)];
    ushort4 rv = *(const ushort4*)&resid[token*CEMB + (lane<<2)];
    float h[4];
    h[0] = bf2f(sv.x) + bf2f(rv.x); h[1] = bf2f(sv.y) + bf2f(rv.y);
    h[2] = bf2f(sv.z) + bf2f(rv.z); h[3] = bf2f(sv.w) + bf2f(rv.w);
    float sum = h[0]+h[1]+h[2]+h[3];
    float sq  = h[0]*h[0]+h[1]*h[1]+h[2]*h[2]+h[3]*h[3];
    for (int off = 1; off < 64; off <<= 1){
        sum += __shfl_xor(sum, off);
        sq  += __shfl_xor(sq, off);
    }
    float mu = sum * (1.0f/256.0f);
    float var = sq * (1.0f/256.0f) - mu*mu;
    float rstd = rsqrtf(var + 1e-5f);
    float4 gv = *(const float4*)&g[lane<<2];
    float4 bv = *(const float4*)&b[lane<<2];
    ushort4 o;
    o.x = f2bf((h[0]-mu)*rstd*gv.x + bv.x);
    o.y = f2bf((h[1]-mu)*rstd*gv.y + bv.y);
    o.z = f2bf((h[2]-mu)*rstd*gv.z + bv.z);
    o.w = f2bf((h[3]-mu)*rstd*gv.w + bv.w);
    *(ushort4*)&out[token*CEMB + (lane<<2)] = o;
}

// ---------------- final scatter: out = backbone + valid * x  ----------------
__global__ __launch_bounds__(256) void scatter_kernel(const float* __restrict__ bb,
    const unsigned short* __restrict__ x, const float* __restrict__ validf,
    float* __restrict__ out)
{
    __shared__ float tile[64][257];
    int bw = blockIdx.x; int b = bw >> 6, w = bw & 63;
    int wh = w >> 3, wwi = w & 7;
    float vf = validf[bw];
    int tid = threadIdx.x;
    for (int c0 = 0; c0 < 256; c0 += 64){
        for (int i = 0; i < 64; ++i){
            int e = i*256 + tid; int t = e >> 6, cc = e & 63;
            tile[cc][t] = bf2f(x[((size_t)bw*256 + t)*CEMB + c0 + cc]);
        }
        __syncthreads();
        for (int i = 0; i < 64; ++i){
            int e = i*256 + tid; int cc = e >> 8, t = e & 255;
            size_t gi = ((size_t)(b*CEMB + c0 + cc)*HH + wh*16 + (t >> 4))*WW + wwi*16 + (t & 15);
            out[gi] = bb[gi] + vf * tile[cc][t];
        }
        __syncthreads();
    }
}

extern "C" void kernel_launch(void* const* d_in, const int* in_sizes, int n_in,
                              void* d_out, int out_size, void* d_ws, size_t ws_size,
                              hipStream_t stream)
{
    (void)in_sizes; (void)n_in; (void)out_size; (void)ws_size;
    const float* backbone = (const float*)d_in[0];
    const float* defe     = (const float*)d_in[1];
    const float* gpe      = (const float*)d_in[3];
    const float* rw1 = (const float*)d_in[4];
    const float* rb1 = (const float*)d_in[5];
    const float* rw2 = (const float*)d_in[6];
    const float* rb2 = (const float*)d_in[7];
    const float* ipw = (const float*)d_in[8];
    const float* ipb = (const float*)d_in[9];
    const float* opw = (const float*)d_in[10];
    const float* opb = (const float*)d_in[11];
    const float* l1w = (const float*)d_in[12];
    const float* l1b = (const float*)d_in[13];
    const float* l2w = (const float*)d_in[14];
    const float* l2b = (const float*)d_in[15];
    const float* g1  = (const float*)d_in[16];
    const float* b1  = (const float*)d_in[17];
    const float* g2  = (const float*)d_in[18];
    const float* b2  = (const float*)d_in[19];

    char* ws = (char*)d_ws;
    unsigned short* pos  = (unsigned short*)(ws);                 //  8,388,608 B
    unsigned short* x    = (unsigned short*)(ws + 8388608);       // 33,554,432 B
    unsigned short* qkv  = (unsigned short*)(ws + 41943040);      // 100,663,296 B (reused: s1/src/s2)
    unsigned short* attn = (unsigned short*)(ws + 142606336);     // 33,554,432 B
    unsigned short* ff   = (unsigned short*)(ws + 176160768);     // 33,554,432 B (one token-chunk)
    float*          validf = (float*)(ws + 209715200);            //      1,024 B
    unsigned short* s1  = qkv;                 // after attention, qkv region is dead
    unsigned short* src = qkv + 16777216;      // element offsets (ushort)
    unsigned short* s2  = qkv + 33554432;
    float* outf = (float*)d_out;

    pos_kernel<<<NW*TT, 256, 0, stream>>>(gpe, rw1, rb1, rw2, rb2, pos);
    valid_kernel<<<BB*NW, 256, 0, stream>>>(defe, validf, outf + (size_t)BB*CEMB*HH*WW);
    partition_kernel<<<BB*NW, 256, 0, stream>>>(backbone, x);

    for (int layer = 0; layer < 2; ++layer){
        // QKV projection: q,k from x+pos (cols < 512), v from x
        gemm_kernel<<<dim3(512, 6), 256, 0, stream>>>(x, CEMB, pos, 512, ipw, CEMB, ipb, qkv, 768, 0);
        if (layer == 0)
            attn_kernel<256, false><<<dim3(BB*NW, NHEAD), 256, 0, stream>>>(qkv, attn, validf);
        else
            attn_kernel<64, true><<<dim3(BB*TT, NHEAD), 256, 0, stream>>>(qkv, attn, validf);
        // out-projection (+bias); residual x added inside LN
        gemm_kernel<<<dim3(512, 2), 256, 0, stream>>>(attn, CEMB, nullptr, 0, opw, CEMB, opb, s1, CEMB, 0);
        ln_kernel<<<NTOK/4, 256, 0, stream>>>(s1, x, g1, b1, src);
        // feed-forward, chunked over tokens (4 x 16384)
        for (int ch = 0; ch < 4; ++ch){
            gemm_kernel<<<dim3(128, 8), 256, 0, stream>>>(src + (size_t)ch*4194304, CEMB, nullptr, 0,
                                                          l1w, CEMB, l1b, ff, DFF, 1);
            gemm_kernel<<<dim3(128, 2), 256, 0, stream>>>(ff, DFF, nullptr, 0,
                                                          l2w, DFF, l2b, s2 + (size_t)ch*4194304, CEMB, 0);
        }
        ln_kernel<<<NTOK/4, 256, 0, stream>>>(s2, src, g2, b2, x);
    }
    scatter_kernel<<<BB*NW, 256, 0, stream>>>(backbone, x, validf, outf);
}

// Round 2
// 1929.973 us; speedup vs baseline: 2.1052x; 2.1052x over previous
//
#include <hip/hip_runtime.h>
#include <hip/hip_bf16.h>

// ---------------- problem constants ----------------
#define CEMB 256
#define NHEAD 8
#define DHEAD 32
#define DFF 1024
#define BB 4
#define HH 128
#define WW 128
#define WSZ 16
#define NWH 8
#define NW 64
#define TT 256            // tokens per window
#define NTOK (BB*NW*TT)   // 65536

typedef __attribute__((ext_vector_type(8))) short bf16x8;
typedef __attribute__((ext_vector_type(4))) float f32x4;

// bf16 helpers (storage type = ushort)
__device__ __forceinline__ float bf2f(unsigned short u){
    union { float f; unsigned int i; } v; v.i = ((unsigned int)u) << 16; return v.f;
}
__device__ __forceinline__ unsigned short f2bf(float f){
    union { float f; unsigned int i; } v; v.f = f;
    unsigned int r = v.i + 0x7fffu + ((v.i >> 16) & 1u);
    return (unsigned short)(r >> 16);
}
__device__ __forceinline__ void unpack8(uint4 v, float* f){
    f[0]=bf2f((unsigned short)(v.x & 0xffff)); f[1]=bf2f((unsigned short)(v.x>>16));
    f[2]=bf2f((unsigned short)(v.y & 0xffff)); f[3]=bf2f((unsigned short)(v.y>>16));
    f[4]=bf2f((unsigned short)(v.z & 0xffff)); f[5]=bf2f((unsigned short)(v.z>>16));
    f[6]=bf2f((unsigned short)(v.w & 0xffff)); f[7]=bf2f((unsigned short)(v.w>>16));
}
__device__ __forceinline__ void async_copy16(const void* g, void* l){
    __builtin_amdgcn_global_load_lds(
        (const __attribute__((address_space(1))) unsigned int*)g,
        (__attribute__((address_space(3))) unsigned int*)l, 16, 0, 0);
}

// ---------------- K1: rel-MLP + pos = gp + rel  ->  pos[nw][T][C] bf16 ----------------
__global__ __launch_bounds__(256) void pos_kernel(const float* __restrict__ gp,
    const float* __restrict__ rw1, const float* __restrict__ rb1,
    const float* __restrict__ rw2, const float* __restrict__ rb2,
    unsigned short* __restrict__ pos)
{
    int wt = blockIdx.x;              // 0..NW*TT-1
    int w = wt >> 8, t = wt & 255;
    int c = threadIdx.x;
    int ty = t >> 4, tx = t & 15;
    float y = ty * (1.0f/15.0f), x = tx * (1.0f/15.0f);
    float acc = rb2[c];
    #pragma unroll 8
    for (int k = 0; k < 64; ++k){
        float h = fmaxf(y*rw1[2*k] + x*rw1[2*k+1] + rb1[k], 0.0f);
        acc += h * rw2[c*64 + k];
    }
    int wh = w >> 3, wwi = w & 7;
    float g = gp[(size_t)c*(HH*WW) + (wh*16 + ty)*WW + wwi*16 + tx];
    pos[(size_t)wt*CEMB + c] = f2bf(g + acc);
}

// ---------------- K2: window validity (max-pool > 0) ----------------
__global__ __launch_bounds__(256) void valid_kernel(const float* __restrict__ defe,
    float* __restrict__ validf, float* __restrict__ tail)
{
    __shared__ float red[4];
    int bw = blockIdx.x; int b = bw >> 6, w = bw & 63;
    int t = threadIdx.x; int ty = t >> 4, tx = t & 15;
    int wh = w >> 3, wwi = w & 7;
    float v = defe[(size_t)b*(HH*WW) + (wh*16+ty)*WW + wwi*16 + tx];
    int lane = t & 63, wave = t >> 6;
    for (int off = 1; off < 64; off <<= 1) v = fmaxf(v, __shfl_xor(v, off));
    if (lane == 0) red[wave] = v;
    __syncthreads();
    if (t == 0){
        float m = fmaxf(fmaxf(red[0], red[1]), fmaxf(red[2], red[3]));
        float r = (m > 0.0f) ? 1.0f : 0.0f;
        validf[bw] = r;
        tail[bw] = r;
    }
}

// ---------------- K3: window partition  backbone[B,C,H,W] -> x[b,w,t,c] bf16 ----------------
__global__ __launch_bounds__(256) void partition_kernel(const float* __restrict__ bb,
    unsigned short* __restrict__ x)
{
    __shared__ float tile[64][257];
    int bw = blockIdx.x; int b = bw >> 6, w = bw & 63;
    int wh = w >> 3, wwi = w & 7;
    int tid = threadIdx.x;
    const float* bbb = bb + (size_t)b*CEMB*HH*WW + (size_t)(wh*16)*WW + wwi*16;
    for (int c0 = 0; c0 < 256; c0 += 64){
        for (int i = 0; i < 64; ++i){
            int e = i*256 + tid; int c = e >> 8, t = e & 255;
            tile[c][t] = bbb[(size_t)(c0 + c)*(HH*WW) + (t >> 4)*WW + (t & 15)];
        }
        __syncthreads();
        for (int i = 0; i < 64; ++i){
            int e = i*256 + tid; int t = e >> 6, cc = e & 63;
            x[((size_t)bw*256 + t)*CEMB + c0 + cc] = f2bf(tile[cc][t]);
        }
        __syncthreads();
    }
}

// ---------------- weight fp32 -> bf16 ----------------
__global__ __launch_bounds__(256) void wcvt_kernel(const float* __restrict__ w,
    unsigned short* __restrict__ o, int n4)
{
    int i = blockIdx.x*256 + threadIdx.x;
    if (i < n4){
        float4 v = ((const float4*)w)[i];
        ushort4 u;
        u.x = f2bf(v.x); u.y = f2bf(v.y); u.z = f2bf(v.z); u.w = f2bf(v.w);
        ((ushort4*)o)[i] = u;
    }
}

// ---------------- xp = x + pos (bf16 elementwise, 8 el/thread) ----------------
__global__ __launch_bounds__(256) void addpos_kernel(const unsigned short* __restrict__ x,
    const unsigned short* __restrict__ pos, unsigned short* __restrict__ xp)
{
    size_t i = ((size_t)blockIdx.x*256 + threadIdx.x) * 8;
    size_t tok = i >> 8; int c = (int)(i & 255);
    size_t pi = ((tok & 16383) << 8) + c;
    uint4 xv = *(const uint4*)&x[i];
    uint4 pv = *(const uint4*)&pos[pi];
    float xf[8], pf[8]; unpack8(xv, xf); unpack8(pv, pf);
    unsigned short o[8];
    #pragma unroll
    for (int j = 0; j < 8; ++j) o[j] = f2bf(xf[j] + pf[j]);
    *(uint4*)&xp[i] = *(uint4*)o;
}

// ---------------- MFMA GEMM: out[M,N](bf16) = A[M,K](bf16) @ W[N,K]^T + bias ----------------
// 128x128 tile, BK=32, 256 threads = 4 waves in 2x2, each wave 64x64 via 4x4 mfma_f32_16x16x32_bf16.
// A-operand rows n0 < nsplit come from A, else A2 (lets one launch do q,k from x+pos and v from x).
__global__ __launch_bounds__(256) void gemm_mfma(
    const unsigned short* __restrict__ A,
    const unsigned short* __restrict__ A2, int nsplit, int ldA,
    const unsigned short* __restrict__ W, int K,
    const float* __restrict__ bias,
    unsigned short* __restrict__ out, int ldO, int relu)
{
    __shared__ unsigned short As[128*32];
    __shared__ unsigned short Bs[128*32];
    const int m0 = blockIdx.x << 7, n0 = blockIdx.y << 7;
    const int tid = threadIdx.x;
    const int lane = tid & 63, wave = tid >> 6;
    const int wm = wave & 1, wn = wave >> 1;
    const int fl = lane & 15, quad = lane >> 4;

    const unsigned short* Ap = ((n0 < nsplit) ? A : A2) + (size_t)m0*ldA;
    const unsigned short* Wp = W + (size_t)n0*K;

    const int c0 = tid, c1 = tid + 256;
    const int r0 = c0 >> 2, o0 = (c0 & 3) << 3;
    const int r1 = c1 >> 2, o1 = (c1 & 3) << 3;

    f32x4 acc[4][4] = {};

    for (int k0 = 0; k0 < K; k0 += 32){
        async_copy16(Ap + (size_t)r0*ldA + k0 + o0, &As[c0 << 3]);
        async_copy16(Ap + (size_t)r1*ldA + k0 + o1, &As[c1 << 3]);
        async_copy16(Wp + (size_t)r0*K   + k0 + o0, &Bs[c0 << 3]);
        async_copy16(Wp + (size_t)r1*K   + k0 + o1, &Bs[c1 << 3]);
        __syncthreads();   // drains vmcnt before barrier (compiler-inserted)
        bf16x8 av[4], bv[4];
        #pragma unroll
        for (int i = 0; i < 4; ++i){
            av[i] = *(const bf16x8*)&As[(wm*64 + i*16 + fl)*32 + quad*8];
            bv[i] = *(const bf16x8*)&Bs[(wn*64 + i*16 + fl)*32 + quad*8];
        }
        #pragma unroll
        for (int i = 0; i < 4; ++i)
            #pragma unroll
            for (int j = 0; j < 4; ++j)
                acc[i][j] = __builtin_amdgcn_mfma_f32_16x16x32_bf16(av[i], bv[j], acc[i][j], 0, 0, 0);
        __syncthreads();
    }

    float bj[4];
    #pragma unroll
    for (int j = 0; j < 4; ++j) bj[j] = bias[n0 + wn*64 + j*16 + fl];
    #pragma unroll
    for (int i = 0; i < 4; ++i){
        int mrow = m0 + wm*64 + i*16 + quad*4;
        #pragma unroll
        for (int j = 0; j < 4; ++j){
            int col = n0 + wn*64 + j*16 + fl;
            #pragma unroll
            for (int r = 0; r < 4; ++r){
                float v = acc[i][j][r] + bj[j];
                if (relu) v = fmaxf(v, 0.0f);
                out[(size_t)(mrow + r)*ldO + col] = f2bf(v);
            }
        }
    }
}

// ---------------- attention: block per (seq, head); fp32 LDS GEMM-structured ----------------
// layer0: L=256, stride=1 token (within-window).  layer1: L=64, stride=256 tokens (cross-window, masked)
template<int L, bool CROSS>
__global__ __launch_bounds__(256) void attn_kernel(const unsigned short* __restrict__ qkv,
    unsigned short* __restrict__ attn_out, const float* __restrict__ validf)
{
    __shared__ float Kt[32][L + 8];      // [d][j]
    __shared__ float Vs[L][36];          // [j][d]
    __shared__ float Qt[32][72];         // [d][q] (q-tile of 64)
    __shared__ float St[L][68];          // [j][q]
    __shared__ float lsum[64];
    __shared__ float vmask[CROSS ? L : 1];

    const int s = blockIdx.x, h = blockIdx.y;
    int base, stride;
    if (CROSS){ int b = s >> 8; base = b*16384 + (s & 255); stride = 256; }
    else      { base = s << 8; stride = 1; }
    const int tid = threadIdx.x;
    const int wave = tid >> 6, lane = tid & 63;
    const float scale = 0.17677669529663687f;

    for (int e = tid; e < L*32; e += 256){
        int j = e >> 5, d = e & 31;
        size_t tok = (size_t)(base + j*stride);
        Kt[d][j] = bf2f(qkv[tok*768 + 256 + h*32 + d]);
        Vs[j][d] = bf2f(qkv[tok*768 + 512 + h*32 + d]);
    }
    if (CROSS){
        for (int e = tid; e < L; e += 256) vmask[e] = validf[(s >> 8)*64 + e];
    }
    __syncthreads();

    for (int q0 = 0; q0 < L; q0 += 64){
        for (int e = tid; e < 64*32; e += 256){
            int q = e >> 5, d = e & 31;
            size_t tok = (size_t)(base + (q0 + q)*stride);
            Qt[d][q] = bf2f(qkv[tok*768 + h*32 + d]);
        }
        __syncthreads();
        // phase A: St[j][q] = scale * sum_d K[j][d] Q[q][d]  (32x32 wave tiles)
        {
            const int jg = lane & 7, qg = lane >> 3;
            const int nTiles = (L/32) * 2;
            for (int tile = wave; tile < nTiles; tile += 4){
                int tj = (tile >> 1) << 5;
                int tq = (tile & 1) << 5;
                float a[4][4] = {{0.0f}};
                #pragma unroll
                for (int d = 0; d < 32; ++d){
                    float4 kv = *(const float4*)&Kt[d][tj + (jg<<2)];
                    float4 qv = *(const float4*)&Qt[d][tq + (qg<<2)];
                    a[0][0] += kv.x*qv.x; a[0][1] += kv.x*qv.y; a[0][2] += kv.x*qv.z; a[0][3] += kv.x*qv.w;
                    a[1][0] += kv.y*qv.x; a[1][1] += kv.y*qv.y; a[1][2] += kv.y*qv.z; a[1][3] += kv.y*qv.w;
                    a[2][0] += kv.z*qv.x; a[2][1] += kv.z*qv.y; a[2][2] += kv.z*qv.z; a[2][3] += kv.z*qv.w;
                    a[3][0] += kv.w*qv.x; a[3][1] += kv.w*qv.y; a[3][2] += kv.w*qv.z; a[3][3] += kv.w*qv.w;
                }
                #pragma unroll
                for (int jj = 0; jj < 4; ++jj){
                    int j = tj + (jg<<2) + jj;
                    float4 sv = make_float4(a[jj][0]*scale, a[jj][1]*scale, a[jj][2]*scale, a[jj][3]*scale);
                    if (CROSS && vmask[j] == 0.0f){ sv.x = sv.y = sv.z = sv.w = -3.0e38f; }
                    *(float4*)&St[j][tq + (qg<<2)] = sv;
                }
            }
        }
        __syncthreads();
        // softmax over j for each query column (wave: 16 q, 4 segments per q)
        {
            const int q = wave*16 + (lane & 15);
            const int seg = lane >> 4;
            float m = -3.4e38f;
            for (int j = seg; j < L; j += 4) m = fmaxf(m, St[j][q]);
            m = fmaxf(m, __shfl_xor(m, 16));
            m = fmaxf(m, __shfl_xor(m, 32));
            float l = 0.0f;
            for (int j = seg; j < L; j += 4){
                float p = __expf(St[j][q] - m);
                St[j][q] = p;
                l += p;
            }
            l += __shfl_xor(l, 16);
            l += __shfl_xor(l, 32);
            if (seg == 0) lsum[q] = l;
        }
        __syncthreads();
        // phase B: O[q][d] = sum_j P[j][q] * V[j][d]; wave: 16 q, lane = (qpair, dgroup)
        {
            const int dg = lane & 7;
            const int qb = wave*16 + ((lane >> 3) & 7)*2;
            float acc0[4] = {0,0,0,0}, acc1[4] = {0,0,0,0};
            #pragma unroll 8
            for (int j = 0; j < L; ++j){
                float2 p = *(const float2*)&St[j][qb];
                float4 v = *(const float4*)&Vs[j][dg<<2];
                acc0[0] += p.x*v.x; acc0[1] += p.x*v.y; acc0[2] += p.x*v.z; acc0[3] += p.x*v.w;
                acc1[0] += p.y*v.x; acc1[1] += p.y*v.y; acc1[2] += p.y*v.z; acc1[3] += p.y*v.w;
            }
            #pragma unroll
            for (int qq = 0; qq < 2; ++qq){
                int q = qb + qq;
                float rl = 1.0f / lsum[q];
                size_t tok = (size_t)(base + (q0 + q)*stride);
                const float* ac = qq ? acc1 : acc0;
                ushort4 st;
                st.x = f2bf(ac[0]*rl); st.y = f2bf(ac[1]*rl);
                st.z = f2bf(ac[2]*rl); st.w = f2bf(ac[3]*rl);
                *(ushort4*)&attn_out[tok*CEMB + h*32 + (dg<<2)] = st;
            }
        }
        __syncthreads();
    }
}

// ---------------- layernorm: out = LN(sin + resid) * g + b  (token per wave) ----------------
__global__ __launch_bounds__(256) void ln_kernel(const unsigned short* __restrict__ sin_,
    const unsigned short* __restrict__ resid, const float* __restrict__ g,
    const float* __restrict__ b, unsigned short* __restrict__ out)
{
    int tid = threadIdx.x;
    int wave = tid >> 6, lane = tid & 63;
    size_t token = (size_t)blockIdx.x*4 + wave;
    ushort4 sv = *(const ushort4*)&sin_[token*CEMB + (lane<<2)];
    ushort4 rv = *(const ushort4*)&resid[token*CEMB + (lane<<2)];
    float h[4];
    h[0] = bf2f(sv.x) + bf2f(rv.x); h[1] = bf2f(sv.y) + bf2f(rv.y);
    h[2] = bf2f(sv.z) + bf2f(rv.z); h[3] = bf2f(sv.w) + bf2f(rv.w);
    float sum = h[0]+h[1]+h[2]+h[3];
    float sq  = h[0]*h[0]+h[1]*h[1]+h[2]*h[2]+h[3]*h[3];
    for (int off = 1; off < 64; off <<= 1){
        sum += __shfl_xor(sum, off);
        sq  += __shfl_xor(sq, off);
    }
    float mu = sum * (1.0f/256.0f);
    float var = sq * (1.0f/256.0f) - mu*mu;
    float rstd = rsqrtf(var + 1e-5f);
    float4 gv = *(const float4*)&g[lane<<2];
    float4 bv = *(const float4*)&b[lane<<2];
    ushort4 o;
    o.x = f2bf((h[0]-mu)*rstd*gv.x + bv.x);
    o.y = f2bf((h[1]-mu)*rstd*gv.y + bv.y);
    o.z = f2bf((h[2]-mu)*rstd*gv.z + bv.z);
    o.w = f2bf((h[3]-mu)*rstd*gv.w + bv.w);
    *(ushort4*)&out[token*CEMB + (lane<<2)] = o;
}

// ---------------- final scatter: out = backbone + valid * x  ----------------
__global__ __launch_bounds__(256) void scatter_kernel(const float* __restrict__ bb,
    const unsigned short* __restrict__ x, const float* __restrict__ validf,
    float* __restrict__ out)
{
    __shared__ float tile[64][257];
    int bw = blockIdx.x; int b = bw >> 6, w = bw & 63;
    int wh = w >> 3, wwi = w & 7;
    float vf = validf[bw];
    int tid = threadIdx.x;
    for (int c0 = 0; c0 < 256; c0 += 64){
        for (int i = 0; i < 64; ++i){
            int e = i*256 + tid; int t = e >> 6, cc = e & 63;
            tile[cc][t] = bf2f(x[((size_t)bw*256 + t)*CEMB + c0 + cc]);
        }
        __syncthreads();
        for (int i = 0; i < 64; ++i){
            int e = i*256 + tid; int cc = e >> 8, t = e & 255;
            size_t gi = ((size_t)(b*CEMB + c0 + cc)*HH + wh*16 + (t >> 4))*WW + wwi*16 + (t & 15);
            out[gi] = bb[gi] + vf * tile[cc][t];
        }
        __syncthreads();
    }
}

extern "C" void kernel_launch(void* const* d_in, const int* in_sizes, int n_in,
                              void* d_out, int out_size, void* d_ws, size_t ws_size,
                              hipStream_t stream)
{
    (void)in_sizes; (void)n_in; (void)out_size; (void)ws_size;
    const float* backbone = (const float*)d_in[0];
    const float* defe     = (const float*)d_in[1];
    const float* gpe      = (const float*)d_in[3];
    const float* rw1 = (const float*)d_in[4];
    const float* rb1 = (const float*)d_in[5];
    const float* rw2 = (const float*)d_in[6];
    const float* rb2 = (const float*)d_in[7];
    const float* ipw = (const float*)d_in[8];
    const float* ipb = (const float*)d_in[9];
    const float* opw = (const float*)d_in[10];
    const float* opb = (const float*)d_in[11];
    const float* l1w = (const float*)d_in[12];
    const float* l1b = (const float*)d_in[13];
    const float* l2w = (const float*)d_in[14];
    const float* l2b = (const float*)d_in[15];
    const float* g1  = (const float*)d_in[16];
    const float* b1  = (const float*)d_in[17];
    const float* g2  = (const float*)d_in[18];
    const float* b2  = (const float*)d_in[19];

    // workspace layout (total ~177.7 MB; R0 used 210 MB so this fits)
    char* ws = (char*)d_ws;
    unsigned short* pos    = (unsigned short*)(ws);               //   8,388,608 B
    unsigned short* x      = (unsigned short*)(ws +   8388608);   //  33,554,432 B
    unsigned short* qkv    = (unsigned short*)(ws +  41943040);   // 100,663,296 B (reused: s1/src/s2)
    unsigned short* shared_= (unsigned short*)(ws + 142606336);   //  33,554,432 B (xp -> attn -> ff, time-shared)
    float*          validf = (float*)(ws + 176160768);            //       1,024 B
    unsigned short* ipw16  = (unsigned short*)(ws + 176161792);   //     393,216 B
    unsigned short* opw16  = (unsigned short*)(ws + 176555008);   //     131,072 B
    unsigned short* l1w16  = (unsigned short*)(ws + 176686080);   //     524,288 B
    unsigned short* l2w16  = (unsigned short*)(ws + 177210368);   //     524,288 B  -> end 177,734,656
    unsigned short* s1  = qkv;                 // after attention, qkv region is dead
    unsigned short* src = qkv + 16777216;      // element offsets (ushort)
    unsigned short* s2  = qkv + 33554432;
    float* outf = (float*)d_out;

    // once-per-launch prep
    wcvt_kernel<<<192, 256, 0, stream>>>(ipw, ipw16, 49152);
    wcvt_kernel<<< 64, 256, 0, stream>>>(opw, opw16, 16384);
    wcvt_kernel<<<256, 256, 0, stream>>>(l1w, l1w16, 65536);
    wcvt_kernel<<<256, 256, 0, stream>>>(l2w, l2w16, 65536);
    pos_kernel<<<NW*TT, 256, 0, stream>>>(gpe, rw1, rb1, rw2, rb2, pos);
    valid_kernel<<<BB*NW, 256, 0, stream>>>(defe, validf, outf + (size_t)BB*CEMB*HH*WW);
    partition_kernel<<<BB*NW, 256, 0, stream>>>(backbone, x);

    const int BIG = 1 << 30;
    for (int layer = 0; layer < 2; ++layer){
        // xp = x + pos (q,k input); v input is x
        addpos_kernel<<<8192, 256, 0, stream>>>(x, pos, shared_);
        gemm_mfma<<<dim3(512, 6), 256, 0, stream>>>(shared_, x, 512, CEMB, ipw16, CEMB, ipb, qkv, 768, 0);
        if (layer == 0)
            attn_kernel<256, false><<<dim3(BB*NW, NHEAD), 256, 0, stream>>>(qkv, shared_, validf);
        else
            attn_kernel<64, true><<<dim3(BB*TT, NHEAD), 256, 0, stream>>>(qkv, shared_, validf);
        gemm_mfma<<<dim3(512, 2), 256, 0, stream>>>(shared_, shared_, BIG, CEMB, opw16, CEMB, opb, s1, CEMB, 0);
        ln_kernel<<<NTOK/4, 256, 0, stream>>>(s1, x, g1, b1, src);
        // feed-forward, chunked over tokens (4 x 16384); ff buffer = shared_ (attn dead)
        for (int ch = 0; ch < 4; ++ch){
            gemm_mfma<<<dim3(128, 8), 256, 0, stream>>>(src + (size_t)ch*4194304, src + (size_t)ch*4194304,
                                                        BIG, CEMB, l1w16, CEMB, l1b, shared_, DFF, 1);
            gemm_mfma<<<dim3(128, 2), 256, 0, stream>>>(shared_, shared_, BIG, DFF, l2w16, DFF, l2b,
                                                        s2 + (size_t)ch*4194304, CEMB, 0);
        }
        ln_kernel<<<NTOK/4, 256, 0, stream>>>(s2, src, g2, b2, x);
    }
    scatter_kernel<<<BB*NW, 256, 0, stream>>>(backbone, x, validf, outf);
}

// Round 3
// 1245.272 us; speedup vs baseline: 3.2628x; 1.5498x over previous
//
#include <hip/hip_runtime.h>
#include <hip/hip_bf16.h>

// ---------------- problem constants ----------------
#define CEMB 256
#define NHEAD 8
#define DHEAD 32
#define DFF 1024
#define BB 4
#define HH 128
#define WW 128
#define WSZ 16
#define NWH 8
#define NW 64
#define TT 256            // tokens per window
#define NTOK (BB*NW*TT)   // 65536

typedef __attribute__((ext_vector_type(8))) short bf16x8;
typedef __attribute__((ext_vector_type(4))) float f32x4;

// bf16 helpers (storage type = ushort)
__device__ __forceinline__ float bf2f(unsigned short u){
    union { float f; unsigned int i; } v; v.i = ((unsigned int)u) << 16; return v.f;
}
__device__ __forceinline__ unsigned short f2bf(float f){
    union { float f; unsigned int i; } v; v.f = f;
    unsigned int r = v.i + 0x7fffu + ((v.i >> 16) & 1u);
    return (unsigned short)(r >> 16);
}
__device__ __forceinline__ void unpack8(uint4 v, float* f){
    f[0]=bf2f((unsigned short)(v.x & 0xffff)); f[1]=bf2f((unsigned short)(v.x>>16));
    f[2]=bf2f((unsigned short)(v.y & 0xffff)); f[3]=bf2f((unsigned short)(v.y>>16));
    f[4]=bf2f((unsigned short)(v.z & 0xffff)); f[5]=bf2f((unsigned short)(v.z>>16));
    f[6]=bf2f((unsigned short)(v.w & 0xffff)); f[7]=bf2f((unsigned short)(v.w>>16));
}
__device__ __forceinline__ void async_copy16(const void* g, void* l){
    __builtin_amdgcn_global_load_lds(
        (const __attribute__((address_space(1))) unsigned int*)g,
        (__attribute__((address_space(3))) unsigned int*)l, 16, 0, 0);
}

// ---------------- K1: rel-MLP + pos = gp + rel  ->  pos[nw][T][C] bf16 ----------------
__global__ __launch_bounds__(256) void pos_kernel(const float* __restrict__ gp,
    const float* __restrict__ rw1, const float* __restrict__ rb1,
    const float* __restrict__ rw2, const float* __restrict__ rb2,
    unsigned short* __restrict__ pos)
{
    int wt = blockIdx.x;              // 0..NW*TT-1
    int w = wt >> 8, t = wt & 255;
    int c = threadIdx.x;
    int ty = t >> 4, tx = t & 15;
    float y = ty * (1.0f/15.0f), x = tx * (1.0f/15.0f);
    float acc = rb2[c];
    #pragma unroll 8
    for (int k = 0; k < 64; ++k){
        float h = fmaxf(y*rw1[2*k] + x*rw1[2*k+1] + rb1[k], 0.0f);
        acc += h * rw2[c*64 + k];
    }
    int wh = w >> 3, wwi = w & 7;
    float g = gp[(size_t)c*(HH*WW) + (wh*16 + ty)*WW + wwi*16 + tx];
    pos[(size_t)wt*CEMB + c] = f2bf(g + acc);
}

// ---------------- K2: window validity (max-pool > 0) ----------------
__global__ __launch_bounds__(256) void valid_kernel(const float* __restrict__ defe,
    float* __restrict__ validf, float* __restrict__ tail)
{
    __shared__ float red[4];
    int bw = blockIdx.x; int b = bw >> 6, w = bw & 63;
    int t = threadIdx.x; int ty = t >> 4, tx = t & 15;
    int wh = w >> 3, wwi = w & 7;
    float v = defe[(size_t)b*(HH*WW) + (wh*16+ty)*WW + wwi*16 + tx];
    int lane = t & 63, wave = t >> 6;
    for (int off = 1; off < 64; off <<= 1) v = fmaxf(v, __shfl_xor(v, off));
    if (lane == 0) red[wave] = v;
    __syncthreads();
    if (t == 0){
        float m = fmaxf(fmaxf(red[0], red[1]), fmaxf(red[2], red[3]));
        float r = (m > 0.0f) ? 1.0f : 0.0f;
        validf[bw] = r;
        tail[bw] = r;
    }
}

// ---------------- K3: window partition  backbone[B,C,H,W] -> x[b,w,t,c] bf16 ----------------
__global__ __launch_bounds__(256) void partition_kernel(const float* __restrict__ bb,
    unsigned short* __restrict__ x)
{
    __shared__ float tile[64][257];
    int bw = blockIdx.x; int b = bw >> 6, w = bw & 63;
    int wh = w >> 3, wwi = w & 7;
    int tid = threadIdx.x;
    const float* bbb = bb + (size_t)b*CEMB*HH*WW + (size_t)(wh*16)*WW + wwi*16;
    for (int c0 = 0; c0 < 256; c0 += 64){
        for (int i = 0; i < 64; ++i){
            int e = i*256 + tid; int c = e >> 8, t = e & 255;
            tile[c][t] = bbb[(size_t)(c0 + c)*(HH*WW) + (t >> 4)*WW + (t & 15)];
        }
        __syncthreads();
        for (int i = 0; i < 64; ++i){
            int e = i*256 + tid; int t = e >> 6, cc = e & 63;
            x[((size_t)bw*256 + t)*CEMB + c0 + cc] = f2bf(tile[cc][t]);
        }
        __syncthreads();
    }
}

// ---------------- weight fp32 -> bf16 ----------------
__global__ __launch_bounds__(256) void wcvt_kernel(const float* __restrict__ w,
    unsigned short* __restrict__ o, int n4)
{
    int i = blockIdx.x*256 + threadIdx.x;
    if (i < n4){
        float4 v = ((const float4*)w)[i];
        ushort4 u;
        u.x = f2bf(v.x); u.y = f2bf(v.y); u.z = f2bf(v.z); u.w = f2bf(v.w);
        ((ushort4*)o)[i] = u;
    }
}

// ---------------- xp = x + pos (bf16 elementwise, 8 el/thread) ----------------
__global__ __launch_bounds__(256) void addpos_kernel(const unsigned short* __restrict__ x,
    const unsigned short* __restrict__ pos, unsigned short* __restrict__ xp)
{
    size_t i = ((size_t)blockIdx.x*256 + threadIdx.x) * 8;
    size_t tok = i >> 8; int c = (int)(i & 255);
    size_t pi = ((tok & 16383) << 8) + c;
    uint4 xv = *(const uint4*)&x[i];
    uint4 pv = *(const uint4*)&pos[pi];
    float xf[8], pf[8]; unpack8(xv, xf); unpack8(pv, pf);
    unsigned short o[8];
    #pragma unroll
    for (int j = 0; j < 8; ++j) o[j] = f2bf(xf[j] + pf[j]);
    *(uint4*)&xp[i] = *(uint4*)o;
}

// ---------------- MFMA GEMM: out[M,N](bf16) = A[M,K](bf16) @ W[N,K]^T + bias ----------------
__global__ __launch_bounds__(256) void gemm_mfma(
    const unsigned short* __restrict__ A,
    const unsigned short* __restrict__ A2, int nsplit, int ldA,
    const unsigned short* __restrict__ W, int K,
    const float* __restrict__ bias,
    unsigned short* __restrict__ out, int ldO, int relu)
{
    __shared__ unsigned short As[128*32];
    __shared__ unsigned short Bs[128*32];
    const int m0 = blockIdx.x << 7, n0 = blockIdx.y << 7;
    const int tid = threadIdx.x;
    const int lane = tid & 63, wave = tid >> 6;
    const int wm = wave & 1, wn = wave >> 1;
    const int fl = lane & 15, quad = lane >> 4;

    const unsigned short* Ap = ((n0 < nsplit) ? A : A2) + (size_t)m0*ldA;
    const unsigned short* Wp = W + (size_t)n0*K;

    const int c0 = tid, c1 = tid + 256;
    const int r0 = c0 >> 2, o0 = (c0 & 3) << 3;
    const int r1 = c1 >> 2, o1 = (c1 & 3) << 3;

    f32x4 acc[4][4] = {};

    for (int k0 = 0; k0 < K; k0 += 32){
        async_copy16(Ap + (size_t)r0*ldA + k0 + o0, &As[c0 << 3]);
        async_copy16(Ap + (size_t)r1*ldA + k0 + o1, &As[c1 << 3]);
        async_copy16(Wp + (size_t)r0*K   + k0 + o0, &Bs[c0 << 3]);
        async_copy16(Wp + (size_t)r1*K   + k0 + o1, &Bs[c1 << 3]);
        __syncthreads();
        bf16x8 av[4], bv[4];
        #pragma unroll
        for (int i = 0; i < 4; ++i){
            av[i] = *(const bf16x8*)&As[(wm*64 + i*16 + fl)*32 + quad*8];
            bv[i] = *(const bf16x8*)&Bs[(wn*64 + i*16 + fl)*32 + quad*8];
        }
        #pragma unroll
        for (int i = 0; i < 4; ++i)
            #pragma unroll
            for (int j = 0; j < 4; ++j)
                acc[i][j] = __builtin_amdgcn_mfma_f32_16x16x32_bf16(av[i], bv[j], acc[i][j], 0, 0, 0);
        __syncthreads();
    }

    float bj[4];
    #pragma unroll
    for (int j = 0; j < 4; ++j) bj[j] = bias[n0 + wn*64 + j*16 + fl];
    #pragma unroll
    for (int i = 0; i < 4; ++i){
        int mrow = m0 + wm*64 + i*16 + quad*4;
        #pragma unroll
        for (int j = 0; j < 4; ++j){
            int col = n0 + wn*64 + j*16 + fl;
            #pragma unroll
            for (int r = 0; r < 4; ++r){
                float v = acc[i][j][r] + bj[j];
                if (relu) v = fmaxf(v, 0.0f);
                out[(size_t)(mrow + r)*ldO + col] = f2bf(v);
            }
        }
    }
}

// ---------------- MFMA flash attention ----------------
// Block per (seq, head), 4 waves. L=256 within-window (stride 1) or L=64 cross-window
// (stride 256, key mask). No-max softmax (scores bounded small); mask applied post-exp.
// QK^T: A=Q[q][d], B=K[j][d] (both natural [idx][k]). PV: A=P[q][j] (LDS round-trip,
// per-wave private so no barriers in the j-loop), B=V^T staged as Vt[d][j].
template<int L, bool CROSS>
__global__ __launch_bounds__(256) void attn_mfma(const unsigned short* __restrict__ qkv,
    unsigned short* __restrict__ attn_out, const float* __restrict__ validf)
{
    constexpr int QW  = (L == 256) ? 64 : 16;  // q rows per wave
    constexpr int MI  = QW / 16;               // m-tiles per wave
    constexpr int VTS = L + 8;                 // Vt row stride (elements), 16B-aligned
    constexpr int LOG = (L == 256) ? 8 : 6;
    __shared__ unsigned short Ks[L*32];        // [j][32]
    __shared__ unsigned short Vt[32*VTS];      // [d][j]
    __shared__ unsigned short Ps[4*QW*72];     // per-wave P tile [q][j0..j0+63], stride 72

    const int s = blockIdx.x, h = blockIdx.y;
    int base, stride;
    if (CROSS){ base = (s >> 8)*16384 + (s & 255); stride = 256; }
    else      { base = s << 8; stride = 1; }
    const int tid = threadIdx.x, lane = tid & 63, wave = tid >> 6;
    const int fl = lane & 15, quad = lane >> 4;
    const float scale = 0.17677669529663687f;

    // stage K rows [j][32] via 16B DMA (lds dest = contiguous per lane: ok)
    for (int cid = tid; cid < L*4; cid += 256){
        int j = cid >> 2, part = cid & 3;
        async_copy16(qkv + (size_t)(base + j*stride)*768 + 256 + h*32 + part*8, &Ks[cid*8]);
    }
    // stage Vt[d][j] (transposed V) manually
    for (int e = tid; e < L*4; e += 256){
        int j = e & (L-1), dp = e >> LOG;
        uint4 vv = *(const uint4*)(qkv + (size_t)(base + j*stride)*768 + 512 + h*32 + dp*8);
        unsigned short tmp[8]; *(uint4*)tmp = vv;
        #pragma unroll
        for (int d = 0; d < 8; ++d) Vt[(dp*8 + d)*VTS + j] = tmp[d];
    }
    __syncthreads();

    // Q fragments (registers, reused over all j)
    bf16x8 qf[MI];
    #pragma unroll
    for (int mi = 0; mi < MI; ++mi){
        int q = wave*QW + mi*16 + fl;
        qf[mi] = *(const bf16x8*)(qkv + (size_t)(base + q*stride)*768 + h*32 + quad*8);
    }
    float vm[4];
    if (CROSS){
        #pragma unroll
        for (int nj = 0; nj < 4; ++nj) vm[nj] = validf[(s >> 8)*64 + nj*16 + fl];
    }

    f32x4 oacc[MI][2] = {};
    float lpart[MI][4] = {};
    unsigned short* Pw = &Ps[wave*QW*72];

    for (int j0 = 0; j0 < L; j0 += 64){
        bf16x8 kf[4];
        #pragma unroll
        for (int nj = 0; nj < 4; ++nj)
            kf[nj] = *(const bf16x8*)&Ks[(j0 + nj*16 + fl)*32 + quad*8];
        f32x4 sacc[MI][4] = {};
        #pragma unroll
        for (int mi = 0; mi < MI; ++mi)
            #pragma unroll
            for (int nj = 0; nj < 4; ++nj)
                sacc[mi][nj] = __builtin_amdgcn_mfma_f32_16x16x32_bf16(qf[mi], kf[nj], sacc[mi][nj], 0, 0, 0);
        // p = exp(s*scale) [* mask]; stash P -> LDS; accumulate per-lane row sums
        #pragma unroll
        for (int mi = 0; mi < MI; ++mi)
            #pragma unroll
            for (int nj = 0; nj < 4; ++nj)
                #pragma unroll
                for (int r = 0; r < 4; ++r){
                    float p = __expf(sacc[mi][nj][r] * scale);
                    if (CROSS) p *= vm[nj];
                    lpart[mi][r] += p;
                    Pw[(mi*16 + quad*4 + r)*72 + nj*16 + fl] = f2bf(p);
                }
        // PV: O += P @ V for this 64-col chunk (reads own wave's P only)
        #pragma unroll
        for (int kk = 0; kk < 2; ++kk){
            bf16x8 vf[2];
            #pragma unroll
            for (int nd = 0; nd < 2; ++nd)
                vf[nd] = *(const bf16x8*)&Vt[(nd*16 + fl)*VTS + j0 + kk*32 + quad*8];
            #pragma unroll
            for (int mi = 0; mi < MI; ++mi){
                bf16x8 pf = *(const bf16x8*)&Pw[(mi*16 + fl)*72 + kk*32 + quad*8];
                #pragma unroll
                for (int nd = 0; nd < 2; ++nd)
                    oacc[mi][nd] = __builtin_amdgcn_mfma_f32_16x16x32_bf16(pf, vf[nd], oacc[mi][nd], 0, 0, 0);
            }
        }
    }

    // reduce row sums across the 16-lane col groups, then write O / l
    #pragma unroll
    for (int mi = 0; mi < MI; ++mi)
        #pragma unroll
        for (int r = 0; r < 4; ++r){
            float l = lpart[mi][r];
            l += __shfl_xor(l, 1); l += __shfl_xor(l, 2);
            l += __shfl_xor(l, 4); l += __shfl_xor(l, 8);
            lpart[mi][r] = 1.0f / l;
        }
    #pragma unroll
    for (int mi = 0; mi < MI; ++mi)
        #pragma unroll
        for (int nd = 0; nd < 2; ++nd)
            #pragma unroll
            for (int r = 0; r < 4; ++r){
                int q = wave*QW + mi*16 + quad*4 + r;
                attn_out[(size_t)(base + q*stride)*CEMB + h*32 + nd*16 + fl] =
                    f2bf(oacc[mi][nd][r] * lpart[mi][r]);
            }
}

// ---------------- layernorm: out = LN(sin + resid) * g + b  (token per wave) ----------------
__global__ __launch_bounds__(256) void ln_kernel(const unsigned short* __restrict__ sin_,
    const unsigned short* __restrict__ resid, const float* __restrict__ g,
    const float* __restrict__ b, unsigned short* __restrict__ out)
{
    int tid = threadIdx.x;
    int wave = tid >> 6, lane = tid & 63;
    size_t token = (size_t)blockIdx.x*4 + wave;
    ushort4 sv = *(const ushort4*)&sin_[token*CEMB + (lane<<2)];
    ushort4 rv = *(const ushort4*)&resid[token*CEMB + (lane<<2)];
    float h[4];
    h[0] = bf2f(sv.x) + bf2f(rv.x); h[1] = bf2f(sv.y) + bf2f(rv.y);
    h[2] = bf2f(sv.z) + bf2f(rv.z); h[3] = bf2f(sv.w) + bf2f(rv.w);
    float sum = h[0]+h[1]+h[2]+h[3];
    float sq  = h[0]*h[0]+h[1]*h[1]+h[2]*h[2]+h[3]*h[3];
    for (int off = 1; off < 64; off <<= 1){
        sum += __shfl_xor(sum, off);
        sq  += __shfl_xor(sq, off);
    }
    float mu = sum * (1.0f/256.0f);
    float var = sq * (1.0f/256.0f) - mu*mu;
    float rstd = rsqrtf(var + 1e-5f);
    float4 gv = *(const float4*)&g[lane<<2];
    float4 bv = *(const float4*)&b[lane<<2];
    ushort4 o;
    o.x = f2bf((h[0]-mu)*rstd*gv.x + bv.x);
    o.y = f2bf((h[1]-mu)*rstd*gv.y + bv.y);
    o.z = f2bf((h[2]-mu)*rstd*gv.z + bv.z);
    o.w = f2bf((h[3]-mu)*rstd*gv.w + bv.w);
    *(ushort4*)&out[token*CEMB + (lane<<2)] = o;
}

// ---------------- final scatter: out = backbone + valid * x  ----------------
__global__ __launch_bounds__(256) void scatter_kernel(const float* __restrict__ bb,
    const unsigned short* __restrict__ x, const float* __restrict__ validf,
    float* __restrict__ out)
{
    __shared__ float tile[64][257];
    int bw = blockIdx.x; int b = bw >> 6, w = bw & 63;
    int wh = w >> 3, wwi = w & 7;
    float vf = validf[bw];
    int tid = threadIdx.x;
    for (int c0 = 0; c0 < 256; c0 += 64){
        for (int i = 0; i < 64; ++i){
            int e = i*256 + tid; int t = e >> 6, cc = e & 63;
            tile[cc][t] = bf2f(x[((size_t)bw*256 + t)*CEMB + c0 + cc]);
        }
        __syncthreads();
        for (int i = 0; i < 64; ++i){
            int e = i*256 + tid; int cc = e >> 8, t = e & 255;
            size_t gi = ((size_t)(b*CEMB + c0 + cc)*HH + wh*16 + (t >> 4))*WW + wwi*16 + (t & 15);
            out[gi] = bb[gi] + vf * tile[cc][t];
        }
        __syncthreads();
    }
}

extern "C" void kernel_launch(void* const* d_in, const int* in_sizes, int n_in,
                              void* d_out, int out_size, void* d_ws, size_t ws_size,
                              hipStream_t stream)
{
    (void)in_sizes; (void)n_in; (void)out_size; (void)ws_size;
    const float* backbone = (const float*)d_in[0];
    const float* defe     = (const float*)d_in[1];
    const float* gpe      = (const float*)d_in[3];
    const float* rw1 = (const float*)d_in[4];
    const float* rb1 = (const float*)d_in[5];
    const float* rw2 = (const float*)d_in[6];
    const float* rb2 = (const float*)d_in[7];
    const float* ipw = (const float*)d_in[8];
    const float* ipb = (const float*)d_in[9];
    const float* opw = (const float*)d_in[10];
    const float* opb = (const float*)d_in[11];
    const float* l1w = (const float*)d_in[12];
    const float* l1b = (const float*)d_in[13];
    const float* l2w = (const float*)d_in[14];
    const float* l2b = (const float*)d_in[15];
    const float* g1  = (const float*)d_in[16];
    const float* b1  = (const float*)d_in[17];
    const float* g2  = (const float*)d_in[18];
    const float* b2  = (const float*)d_in[19];

    char* ws = (char*)d_ws;
    unsigned short* pos    = (unsigned short*)(ws);               //   8,388,608 B
    unsigned short* x      = (unsigned short*)(ws +   8388608);   //  33,554,432 B
    unsigned short* qkv    = (unsigned short*)(ws +  41943040);   // 100,663,296 B (reused: s1/src/s2)
    unsigned short* shared_= (unsigned short*)(ws + 142606336);   //  33,554,432 B (xp -> attn -> ff)
    float*          validf = (float*)(ws + 176160768);            //       1,024 B
    unsigned short* ipw16  = (unsigned short*)(ws + 176161792);
    unsigned short* opw16  = (unsigned short*)(ws + 176555008);
    unsigned short* l1w16  = (unsigned short*)(ws + 176686080);
    unsigned short* l2w16  = (unsigned short*)(ws + 177210368);
    unsigned short* s1  = qkv;
    unsigned short* src = qkv + 16777216;
    unsigned short* s2  = qkv + 33554432;
    float* outf = (float*)d_out;

    wcvt_kernel<<<192, 256, 0, stream>>>(ipw, ipw16, 49152);
    wcvt_kernel<<< 64, 256, 0, stream>>>(opw, opw16, 16384);
    wcvt_kernel<<<256, 256, 0, stream>>>(l1w, l1w16, 65536);
    wcvt_kernel<<<256, 256, 0, stream>>>(l2w, l2w16, 65536);
    pos_kernel<<<NW*TT, 256, 0, stream>>>(gpe, rw1, rb1, rw2, rb2, pos);
    valid_kernel<<<BB*NW, 256, 0, stream>>>(defe, validf, outf + (size_t)BB*CEMB*HH*WW);
    partition_kernel<<<BB*NW, 256, 0, stream>>>(backbone, x);

    const int BIG = 1 << 30;
    for (int layer = 0; layer < 2; ++layer){
        addpos_kernel<<<8192, 256, 0, stream>>>(x, pos, shared_);
        gemm_mfma<<<dim3(512, 6), 256, 0, stream>>>(shared_, x, 512, CEMB, ipw16, CEMB, ipb, qkv, 768, 0);
        if (layer == 0)
            attn_mfma<256, false><<<dim3(BB*NW, NHEAD), 256, 0, stream>>>(qkv, shared_, validf);
        else
            attn_mfma<64, true><<<dim3(BB*TT, NHEAD), 256, 0, stream>>>(qkv, shared_, validf);
        gemm_mfma<<<dim3(512, 2), 256, 0, stream>>>(shared_, shared_, BIG, CEMB, opw16, CEMB, opb, s1, CEMB, 0);
        ln_kernel<<<NTOK/4, 256, 0, stream>>>(s1, x, g1, b1, src);
        for (int ch = 0; ch < 4; ++ch){
            gemm_mfma<<<dim3(128, 8), 256, 0, stream>>>(src + (size_t)ch*4194304, src + (size_t)ch*4194304,
                                                        BIG, CEMB, l1w16, CEMB, l1b, shared_, DFF, 1);
            gemm_mfma<<<dim3(128, 2), 256, 0, stream>>>(shared_, shared_, BIG, DFF, l2w16, DFF, l2b,
                                                        s2 + (size_t)ch*4194304, CEMB, 0);
        }
        ln_kernel<<<NTOK/4, 256, 0, stream>>>(s2, src, g2, b2, x);
    }
    scatter_kernel<<<BB*NW, 256, 0, stream>>>(backbone, x, validf, outf);
}

// Round 4
// 1171.154 us; speedup vs baseline: 3.4692x; 1.0633x over previous
//
#include <hip/hip_runtime.h>
#include <hip/hip_bf16.h>

// ---------------- problem constants ----------------
#define CEMB 256
#define NHEAD 8
#define DHEAD 32
#define DFF 1024
#define BB 4
#define HH 128
#define WW 128
#define WSZ 16
#define NWH 8
#define NW 64
#define TT 256            // tokens per window
#define NTOK (BB*NW*TT)   // 65536

typedef __attribute__((ext_vector_type(8))) short bf16x8;
typedef __attribute__((ext_vector_type(4))) float f32x4;

// bf16 helpers (storage type = ushort)
__device__ __forceinline__ float bf2f(unsigned short u){
    union { float f; unsigned int i; } v; v.i = ((unsigned int)u) << 16; return v.f;
}
__device__ __forceinline__ unsigned short f2bf(float f){
    union { float f; unsigned int i; } v; v.f = f;
    unsigned int r = v.i + 0x7fffu + ((v.i >> 16) & 1u);
    return (unsigned short)(r >> 16);
}
__device__ __forceinline__ void unpack8(uint4 v, float* f){
    f[0]=bf2f((unsigned short)(v.x & 0xffff)); f[1]=bf2f((unsigned short)(v.x>>16));
    f[2]=bf2f((unsigned short)(v.y & 0xffff)); f[3]=bf2f((unsigned short)(v.y>>16));
    f[4]=bf2f((unsigned short)(v.z & 0xffff)); f[5]=bf2f((unsigned short)(v.z>>16));
    f[6]=bf2f((unsigned short)(v.w & 0xffff)); f[7]=bf2f((unsigned short)(v.w>>16));
}
__device__ __forceinline__ void async_copy16(const void* g, void* l){
    __builtin_amdgcn_global_load_lds(
        (const __attribute__((address_space(1))) unsigned int*)g,
        (__attribute__((address_space(3))) unsigned int*)l, 16, 0, 0);
}

// ---------------- rel MLP: rel[t][c] fp32 (once) ----------------
__global__ __launch_bounds__(256) void rel_kernel(const float* __restrict__ rw1,
    const float* __restrict__ rb1, const float* __restrict__ rw2,
    const float* __restrict__ rb2, float* __restrict__ rel)
{
    __shared__ float hsh[64];
    int t = blockIdx.x, c = threadIdx.x;
    int ty = t >> 4, tx = t & 15;
    if (c < 64){
        float y = ty*(1.0f/15.0f), xx = tx*(1.0f/15.0f);
        hsh[c] = fmaxf(y*rw1[2*c] + xx*rw1[2*c+1] + rb1[c], 0.0f);
    }
    __syncthreads();
    float acc = rb2[c];
    #pragma unroll 16
    for (int k = 0; k < 64; ++k) acc += hsh[k]*rw2[c*64 + k];
    rel[t*256 + c] = acc;
}

// ---------------- pos[w][t][c] = gp^T + rel  (coalesced LDS transpose) ----------------
__global__ __launch_bounds__(256) void posT_kernel(const float* __restrict__ gp,
    const float* __restrict__ rel, unsigned short* __restrict__ pos)
{
    __shared__ float tile[64][257];
    int w = blockIdx.x & 63, c0 = (blockIdx.x >> 6) << 6;
    int wh = w >> 3, wwi = w & 7;
    int tid = threadIdx.x;
    const float* gpb = gp + (size_t)c0*(HH*WW) + (size_t)(wh*16)*WW + wwi*16;
    for (int i = 0; i < 64; ++i){
        int e = i*256 + tid; int c = e >> 8, t = e & 255;
        tile[c][t] = gpb[(size_t)c*(HH*WW) + (t >> 4)*WW + (t & 15)];
    }
    __syncthreads();
    for (int i = 0; i < 64; ++i){
        int e = i*256 + tid; int t = e >> 6, cc = e & 63;
        pos[((size_t)w*256 + t)*CEMB + c0 + cc] = f2bf(tile[cc][t] + rel[t*256 + c0 + cc]);
    }
}

// ---------------- K2: window validity (max-pool > 0) ----------------
__global__ __launch_bounds__(256) void valid_kernel(const float* __restrict__ defe,
    float* __restrict__ validf, float* __restrict__ tail)
{
    __shared__ float red[4];
    int bw = blockIdx.x; int b = bw >> 6, w = bw & 63;
    int t = threadIdx.x; int ty = t >> 4, tx = t & 15;
    int wh = w >> 3, wwi = w & 7;
    float v = defe[(size_t)b*(HH*WW) + (wh*16+ty)*WW + wwi*16 + tx];
    int lane = t & 63, wave = t >> 6;
    for (int off = 1; off < 64; off <<= 1) v = fmaxf(v, __shfl_xor(v, off));
    if (lane == 0) red[wave] = v;
    __syncthreads();
    if (t == 0){
        float m = fmaxf(fmaxf(red[0], red[1]), fmaxf(red[2], red[3]));
        float r = (m > 0.0f) ? 1.0f : 0.0f;
        validf[bw] = r;
        tail[bw] = r;
    }
}

// ---------------- K3: window partition  backbone[B,C,H,W] -> x[b,w,t,c] bf16 ----------------
__global__ __launch_bounds__(256) void partition_kernel(const float* __restrict__ bb,
    unsigned short* __restrict__ x)
{
    __shared__ float tile[64][257];
    int bw = blockIdx.x; int b = bw >> 6, w = bw & 63;
    int wh = w >> 3, wwi = w & 7;
    int tid = threadIdx.x;
    const float* bbb = bb + (size_t)b*CEMB*HH*WW + (size_t)(wh*16)*WW + wwi*16;
    for (int c0 = 0; c0 < 256; c0 += 64){
        for (int i = 0; i < 64; ++i){
            int e = i*256 + tid; int c = e >> 8, t = e & 255;
            tile[c][t] = bbb[(size_t)(c0 + c)*(HH*WW) + (t >> 4)*WW + (t & 15)];
        }
        __syncthreads();
        for (int i = 0; i < 64; ++i){
            int e = i*256 + tid; int t = e >> 6, cc = e & 63;
            x[((size_t)bw*256 + t)*CEMB + c0 + cc] = f2bf(tile[cc][t]);
        }
        __syncthreads();
    }
}

// ---------------- weight fp32 -> bf16 ----------------
__global__ __launch_bounds__(256) void wcvt_kernel(const float* __restrict__ w,
    unsigned short* __restrict__ o, int n4)
{
    int i = blockIdx.x*256 + threadIdx.x;
    if (i < n4){
        float4 v = ((const float4*)w)[i];
        ushort4 u;
        u.x = f2bf(v.x); u.y = f2bf(v.y); u.z = f2bf(v.z); u.w = f2bf(v.w);
        ((ushort4*)o)[i] = u;
    }
}

// ---------------- xp = x + pos (bf16 elementwise, 8 el/thread) ----------------
__global__ __launch_bounds__(256) void addpos_kernel(const unsigned short* __restrict__ x,
    const unsigned short* __restrict__ pos, unsigned short* __restrict__ xp)
{
    size_t i = ((size_t)blockIdx.x*256 + threadIdx.x) * 8;
    size_t tok = i >> 8; int c = (int)(i & 255);
    size_t pi = ((tok & 16383) << 8) + c;
    uint4 xv = *(const uint4*)&x[i];
    uint4 pv = *(const uint4*)&pos[pi];
    float xf[8], pf[8]; unpack8(xv, xf); unpack8(pv, pf);
    unsigned short o[8];
    #pragma unroll
    for (int j = 0; j < 8; ++j) o[j] = f2bf(xf[j] + pf[j]);
    *(uint4*)&xp[i] = *(uint4*)o;
}

// ---------------- MFMA GEMM: out[M,N](bf16) = A[M,K](bf16) @ W[N,K]^T + bias ----------------
__global__ __launch_bounds__(256) void gemm_mfma(
    const unsigned short* __restrict__ A,
    const unsigned short* __restrict__ A2, int nsplit, int ldA,
    const unsigned short* __restrict__ W, int K,
    const float* __restrict__ bias,
    unsigned short* __restrict__ out, int ldO, int relu)
{
    __shared__ unsigned short As[128*32];
    __shared__ unsigned short Bs[128*32];
    const int m0 = blockIdx.x << 7, n0 = blockIdx.y << 7;
    const int tid = threadIdx.x;
    const int lane = tid & 63, wave = tid >> 6;
    const int wm = wave & 1, wn = wave >> 1;
    const int fl = lane & 15, quad = lane >> 4;

    const unsigned short* Ap = ((n0 < nsplit) ? A : A2) + (size_t)m0*ldA;
    const unsigned short* Wp = W + (size_t)n0*K;

    const int c0 = tid, c1 = tid + 256;
    const int r0 = c0 >> 2, o0 = (c0 & 3) << 3;
    const int r1 = c1 >> 2, o1 = (c1 & 3) << 3;

    f32x4 acc[4][4] = {};

    for (int k0 = 0; k0 < K; k0 += 32){
        async_copy16(Ap + (size_t)r0*ldA + k0 + o0, &As[c0 << 3]);
        async_copy16(Ap + (size_t)r1*ldA + k0 + o1, &As[c1 << 3]);
        async_copy16(Wp + (size_t)r0*K   + k0 + o0, &Bs[c0 << 3]);
        async_copy16(Wp + (size_t)r1*K   + k0 + o1, &Bs[c1 << 3]);
        __syncthreads();
        bf16x8 av[4], bv[4];
        #pragma unroll
        for (int i = 0; i < 4; ++i){
            av[i] = *(const bf16x8*)&As[(wm*64 + i*16 + fl)*32 + quad*8];
            bv[i] = *(const bf16x8*)&Bs[(wn*64 + i*16 + fl)*32 + quad*8];
        }
        #pragma unroll
        for (int i = 0; i < 4; ++i)
            #pragma unroll
            for (int j = 0; j < 4; ++j)
                acc[i][j] = __builtin_amdgcn_mfma_f32_16x16x32_bf16(av[i], bv[j], acc[i][j], 0, 0, 0);
        __syncthreads();
    }

    float bj[4];
    #pragma unroll
    for (int j = 0; j < 4; ++j) bj[j] = bias[n0 + wn*64 + j*16 + fl];
    #pragma unroll
    for (int i = 0; i < 4; ++i){
        int mrow = m0 + wm*64 + i*16 + quad*4;
        #pragma unroll
        for (int j = 0; j < 4; ++j){
            int col = n0 + wn*64 + j*16 + fl;
            #pragma unroll
            for (int r = 0; r < 4; ++r){
                float v = acc[i][j][r] + bj[j];
                if (relu) v = fmaxf(v, 0.0f);
                out[(size_t)(mrow + r)*ldO + col] = f2bf(v);
            }
        }
    }
}

// ---------------- MFMA GEMM + residual + LayerNorm (N == 256 exactly) ----------------
// out[M,256] = LN( A[M,K] @ W[256,K]^T + bias + resid ) * g + b
// 128x256 tile, 4 waves 2x2 (wm: 64 rows, wn: 128 cols). Each block owns full rows ->
// LN fused in epilogue: fl-butterfly + cross-wave LDS reduction for row mean/var.
__global__ __launch_bounds__(256, 2) void gemm_ln(
    const unsigned short* __restrict__ A, int K,
    const unsigned short* __restrict__ W,
    const float* __restrict__ bias,
    const unsigned short* __restrict__ resid,
    const float* __restrict__ g, const float* __restrict__ b,
    unsigned short* __restrict__ out)
{
    __shared__ unsigned short As[128*32];
    __shared__ unsigned short Bs[256*32];
    __shared__ float psum[2][128];
    __shared__ float psq[2][128];
    const int m0 = blockIdx.x << 7;
    const int tid = threadIdx.x, lane = tid & 63, wave = tid >> 6;
    const int wm = wave & 1, wn = wave >> 1;
    const int fl = lane & 15, quad = lane >> 4;

    const unsigned short* Ap = A + (size_t)m0*K;

    f32x4 acc[4][8] = {};

    for (int k0 = 0; k0 < K; k0 += 32){
        {
            int c0 = tid, c1 = tid + 256;
            async_copy16(Ap + (size_t)(c0 >> 2)*K + k0 + ((c0 & 3) << 3), &As[c0 << 3]);
            async_copy16(Ap + (size_t)(c1 >> 2)*K + k0 + ((c1 & 3) << 3), &As[c1 << 3]);
        }
        #pragma unroll
        for (int t = 0; t < 4; ++t){
            int c = tid + t*256;
            async_copy16(W + (size_t)(c >> 2)*K + k0 + ((c & 3) << 3), &Bs[c << 3]);
        }
        __syncthreads();
        bf16x8 av[4], bv[8];
        #pragma unroll
        for (int i = 0; i < 4; ++i)
            av[i] = *(const bf16x8*)&As[(wm*64 + i*16 + fl)*32 + quad*8];
        #pragma unroll
        for (int j = 0; j < 8; ++j)
            bv[j] = *(const bf16x8*)&Bs[(wn*128 + j*16 + fl)*32 + quad*8];
        #pragma unroll
        for (int i = 0; i < 4; ++i)
            #pragma unroll
            for (int j = 0; j < 8; ++j)
                acc[i][j] = __builtin_amdgcn_mfma_f32_16x16x32_bf16(av[i], bv[j], acc[i][j], 0, 0, 0);
        __syncthreads();
    }

    float bcol[8], gcol[8], bbcol[8];
    #pragma unroll
    for (int j = 0; j < 8; ++j){
        int col = wn*128 + j*16 + fl;
        bcol[j] = bias[col]; gcol[j] = g[col]; bbcol[j] = b[col];
    }
    // h = acc + bias + resid (in place); per-row partial sums
    float s[4][4] = {{0}}, sq[4][4] = {{0}};
    #pragma unroll
    for (int i = 0; i < 4; ++i)
        #pragma unroll
        for (int r = 0; r < 4; ++r){
            int row = m0 + wm*64 + i*16 + quad*4 + r;
            #pragma unroll
            for (int j = 0; j < 8; ++j){
                float h = acc[i][j][r] + bcol[j]
                        + bf2f(resid[(size_t)row*256 + wn*128 + j*16 + fl]);
                acc[i][j][r] = h;
                s[i][r] += h; sq[i][r] += h*h;
            }
        }
    #pragma unroll
    for (int i = 0; i < 4; ++i)
        #pragma unroll
        for (int r = 0; r < 4; ++r){
            float ss = s[i][r], qq = sq[i][r];
            ss += __shfl_xor(ss, 1); qq += __shfl_xor(qq, 1);
            ss += __shfl_xor(ss, 2); qq += __shfl_xor(qq, 2);
            ss += __shfl_xor(ss, 4); qq += __shfl_xor(qq, 4);
            ss += __shfl_xor(ss, 8); qq += __shfl_xor(qq, 8);
            if (fl == 0){
                int lr = wm*64 + i*16 + quad*4 + r;
                psum[wn][lr] = ss; psq[wn][lr] = qq;
            }
        }
    __syncthreads();
    #pragma unroll
    for (int i = 0; i < 4; ++i)
        #pragma unroll
        for (int r = 0; r < 4; ++r){
            int lr = wm*64 + i*16 + quad*4 + r;
            float mu  = (psum[0][lr] + psum[1][lr]) * (1.0f/256.0f);
            float var = (psq[0][lr] + psq[1][lr]) * (1.0f/256.0f) - mu*mu;
            float rstd = rsqrtf(var + 1e-5f);
            #pragma unroll
            for (int j = 0; j < 8; ++j){
                int col = wn*128 + j*16 + fl;
                out[(size_t)(m0 + lr)*256 + col] =
                    f2bf((acc[i][j][r] - mu)*rstd*gcol[j] + bbcol[j]);
            }
        }
}

// ---------------- MFMA flash attention ----------------
template<int L, bool CROSS>
__global__ __launch_bounds__(256) void attn_mfma(const unsigned short* __restrict__ qkv,
    unsigned short* __restrict__ attn_out, const float* __restrict__ validf)
{
    constexpr int QW  = (L == 256) ? 64 : 16;  // q rows per wave
    constexpr int MI  = QW / 16;               // m-tiles per wave
    constexpr int VTS = L + 8;                 // Vt row stride, 16B-aligned
    constexpr int LOG = (L == 256) ? 8 : 6;
    __shared__ unsigned short Ks[L*32];        // [j][32]
    __shared__ unsigned short Vt[32*VTS];      // [d][j]
    __shared__ unsigned short Ps[4*QW*72];     // per-wave P tile [q][j], stride 72

    const int s = blockIdx.x, h = blockIdx.y;
    int base, stride;
    if (CROSS){ base = (s >> 8)*16384 + (s & 255); stride = 256; }
    else      { base = s << 8; stride = 1; }
    const int tid = threadIdx.x, lane = tid & 63, wave = tid >> 6;
    const int fl = lane & 15, quad = lane >> 4;
    const float scale = 0.17677669529663687f;

    for (int cid = tid; cid < L*4; cid += 256){
        int j = cid >> 2, part = cid & 3;
        async_copy16(qkv + (size_t)(base + j*stride)*768 + 256 + h*32 + part*8, &Ks[cid*8]);
    }
    for (int e = tid; e < L*4; e += 256){
        int j = e & (L-1), dp = e >> LOG;
        uint4 vv = *(const uint4*)(qkv + (size_t)(base + j*stride)*768 + 512 + h*32 + dp*8);
        unsigned short tmp[8]; *(uint4*)tmp = vv;
        #pragma unroll
        for (int d = 0; d < 8; ++d) Vt[(dp*8 + d)*VTS + j] = tmp[d];
    }
    __syncthreads();

    bf16x8 qf[MI];
    #pragma unroll
    for (int mi = 0; mi < MI; ++mi){
        int q = wave*QW + mi*16 + fl;
        qf[mi] = *(const bf16x8*)(qkv + (size_t)(base + q*stride)*768 + h*32 + quad*8);
    }
    float vm[4];
    if (CROSS){
        #pragma unroll
        for (int nj = 0; nj < 4; ++nj) vm[nj] = validf[(s >> 8)*64 + nj*16 + fl];
    }

    f32x4 oacc[MI][2] = {};
    float lpart[MI][4] = {};
    unsigned short* Pw = &Ps[wave*QW*72];

    for (int j0 = 0; j0 < L; j0 += 64){
        bf16x8 kf[4];
        #pragma unroll
        for (int nj = 0; nj < 4; ++nj)
            kf[nj] = *(const bf16x8*)&Ks[(j0 + nj*16 + fl)*32 + quad*8];
        f32x4 sacc[MI][4] = {};
        #pragma unroll
        for (int mi = 0; mi < MI; ++mi)
            #pragma unroll
            for (int nj = 0; nj < 4; ++nj)
                sacc[mi][nj] = __builtin_amdgcn_mfma_f32_16x16x32_bf16(qf[mi], kf[nj], sacc[mi][nj], 0, 0, 0);
        #pragma unroll
        for (int mi = 0; mi < MI; ++mi)
            #pragma unroll
            for (int nj = 0; nj < 4; ++nj)
                #pragma unroll
                for (int r = 0; r < 4; ++r){
                    float p = __expf(sacc[mi][nj][r] * scale);
                    if (CROSS) p *= vm[nj];
                    lpart[mi][r] += p;
                    Pw[(mi*16 + quad*4 + r)*72 + nj*16 + fl] = f2bf(p);
                }
        #pragma unroll
        for (int kk = 0; kk < 2; ++kk){
            bf16x8 vf[2];
            #pragma unroll
            for (int nd = 0; nd < 2; ++nd)
                vf[nd] = *(const bf16x8*)&Vt[(nd*16 + fl)*VTS + j0 + kk*32 + quad*8];
            #pragma unroll
            for (int mi = 0; mi < MI; ++mi){
                bf16x8 pf = *(const bf16x8*)&Pw[(mi*16 + fl)*72 + kk*32 + quad*8];
                #pragma unroll
                for (int nd = 0; nd < 2; ++nd)
                    oacc[mi][nd] = __builtin_amdgcn_mfma_f32_16x16x32_bf16(pf, vf[nd], oacc[mi][nd], 0, 0, 0);
            }
        }
    }

    #pragma unroll
    for (int mi = 0; mi < MI; ++mi)
        #pragma unroll
        for (int r = 0; r < 4; ++r){
            float l = lpart[mi][r];
            l += __shfl_xor(l, 1); l += __shfl_xor(l, 2);
            l += __shfl_xor(l, 4); l += __shfl_xor(l, 8);
            lpart[mi][r] = 1.0f / l;
        }
    #pragma unroll
    for (int mi = 0; mi < MI; ++mi)
        #pragma unroll
        for (int nd = 0; nd < 2; ++nd)
            #pragma unroll
            for (int r = 0; r < 4; ++r){
                int q = wave*QW + mi*16 + quad*4 + r;
                attn_out[(size_t)(base + q*stride)*CEMB + h*32 + nd*16 + fl] =
                    f2bf(oacc[mi][nd][r] * lpart[mi][r]);
            }
}

// ---------------- final scatter: out = backbone + valid * x  ----------------
__global__ __launch_bounds__(256) void scatter_kernel(const float* __restrict__ bb,
    const unsigned short* __restrict__ x, const float* __restrict__ validf,
    float* __restrict__ out)
{
    __shared__ float tile[64][257];
    int bw = blockIdx.x; int b = bw >> 6, w = bw & 63;
    int wh = w >> 3, wwi = w & 7;
    float vf = validf[bw];
    int tid = threadIdx.x;
    for (int c0 = 0; c0 < 256; c0 += 64){
        for (int i = 0; i < 64; ++i){
            int e = i*256 + tid; int t = e >> 6, cc = e & 63;
            tile[cc][t] = bf2f(x[((size_t)bw*256 + t)*CEMB + c0 + cc]);
        }
        __syncthreads();
        for (int i = 0; i < 64; ++i){
            int e = i*256 + tid; int cc = e >> 8, t = e & 255;
            size_t gi = ((size_t)(b*CEMB + c0 + cc)*HH + wh*16 + (t >> 4))*WW + wwi*16 + (t & 15);
            out[gi] = bb[gi] + vf * tile[cc][t];
        }
        __syncthreads();
    }
}

extern "C" void kernel_launch(void* const* d_in, const int* in_sizes, int n_in,
                              void* d_out, int out_size, void* d_ws, size_t ws_size,
                              hipStream_t stream)
{
    (void)in_sizes; (void)n_in; (void)out_size; (void)ws_size;
    const float* backbone = (const float*)d_in[0];
    const float* defe     = (const float*)d_in[1];
    const float* gpe      = (const float*)d_in[3];
    const float* rw1 = (const float*)d_in[4];
    const float* rb1 = (const float*)d_in[5];
    const float* rw2 = (const float*)d_in[6];
    const float* rb2 = (const float*)d_in[7];
    const float* ipw = (const float*)d_in[8];
    const float* ipb = (const float*)d_in[9];
    const float* opw = (const float*)d_in[10];
    const float* opb = (const float*)d_in[11];
    const float* l1w = (const float*)d_in[12];
    const float* l1b = (const float*)d_in[13];
    const float* l2w = (const float*)d_in[14];
    const float* l2b = (const float*)d_in[15];
    const float* g1  = (const float*)d_in[16];
    const float* b1  = (const float*)d_in[17];
    const float* g2  = (const float*)d_in[18];
    const float* b2  = (const float*)d_in[19];

    // workspace layout (ends ~178 MB; R0 proved >= 210 MB available)
    char* ws = (char*)d_ws;
    unsigned short* pos    = (unsigned short*)(ws);               //   8,388,608
    unsigned short* x      = (unsigned short*)(ws +   8388608);   //  33,554,432
    unsigned short* qkv    = (unsigned short*)(ws +  41943040);   // 100,663,296 (later: src + ff)
    unsigned short* shared_= (unsigned short*)(ws + 142606336);   //  33,554,432 (xp -> attn)
    float*          validf = (float*)(ws + 176160768);            //       1,024
    unsigned short* ipw16  = (unsigned short*)(ws + 176161792);   //     393,216
    unsigned short* opw16  = (unsigned short*)(ws + 176555008);   //     131,072
    unsigned short* l1w16  = (unsigned short*)(ws + 176686080);   //     524,288
    unsigned short* l2w16  = (unsigned short*)(ws + 177210368);   //     524,288
    float*          rel    = (float*)(ws + 177734656);            //     262,144 -> end 177,996,800
    unsigned short* src = qkv;                       // overlays qkv (dead post-attn)
    unsigned short* ff  = qkv + 16777216;            // 67 MB, overlays qkv tail
    float* outf = (float*)d_out;

    wcvt_kernel<<<192, 256, 0, stream>>>(ipw, ipw16, 49152);
    wcvt_kernel<<< 64, 256, 0, stream>>>(opw, opw16, 16384);
    wcvt_kernel<<<256, 256, 0, stream>>>(l1w, l1w16, 65536);
    wcvt_kernel<<<256, 256, 0, stream>>>(l2w, l2w16, 65536);
    rel_kernel<<<256, 256, 0, stream>>>(rw1, rb1, rw2, rb2, rel);
    posT_kernel<<<256, 256, 0, stream>>>(gpe, rel, pos);
    valid_kernel<<<BB*NW, 256, 0, stream>>>(defe, validf, outf + (size_t)BB*CEMB*HH*WW);
    partition_kernel<<<BB*NW, 256, 0, stream>>>(backbone, x);

    for (int layer = 0; layer < 2; ++layer){
        addpos_kernel<<<8192, 256, 0, stream>>>(x, pos, shared_);
        gemm_mfma<<<dim3(512, 6), 256, 0, stream>>>(shared_, x, 512, CEMB, ipw16, CEMB, ipb, qkv, 768, 0);
        if (layer == 0)
            attn_mfma<256, false><<<dim3(BB*NW, NHEAD), 256, 0, stream>>>(qkv, shared_, validf);
        else
            attn_mfma<64, true><<<dim3(BB*TT, NHEAD), 256, 0, stream>>>(qkv, shared_, validf);
        // out_proj + residual(x) + LN1 -> src   (qkv dead from here; src overlays it)
        gemm_ln<<<dim3(512, 1), 256, 0, stream>>>(shared_, CEMB, opw16, opb, x, g1, b1, src);
        // feed-forward, 2 chunks of 32768 tokens; ff overlays qkv tail
        for (int ch = 0; ch < 2; ++ch){
            const int BIG = 1 << 30;
            unsigned short* srcC = src + (size_t)ch*8388608;
            gemm_mfma<<<dim3(256, 8), 256, 0, stream>>>(srcC, srcC, BIG, CEMB, l1w16, CEMB, l1b, ff, DFF, 1);
            // lin2 + residual(src) + LN2 -> x
            gemm_ln<<<dim3(256, 1), 256, 0, stream>>>(ff, DFF, l2w16, l2b, srcC, g2, b2,
                                                      x + (size_t)ch*8388608);
        }
    }
    scatter_kernel<<<BB*NW, 256, 0, stream>>>(backbone, x, validf, outf);
}

// Round 5
// 949.847 us; speedup vs baseline: 4.2775x; 1.2330x over previous
//
#include <hip/hip_runtime.h>
#include <hip/hip_bf16.h>

// ---------------- problem constants ----------------
#define CEMB 256
#define NHEAD 8
#define DHEAD 32
#define DFF 1024
#define BB 4
#define HH 128
#define WW 128
#define WSZ 16
#define NWH 8
#define NW 64
#define TT 256            // tokens per window
#define NTOK (BB*NW*TT)   // 65536

typedef __attribute__((ext_vector_type(8))) short bf16x8;
typedef __attribute__((ext_vector_type(4))) float f32x4;

// bf16 helpers (storage type = ushort)
__device__ __forceinline__ float bf2f(unsigned short u){
    union { float f; unsigned int i; } v; v.i = ((unsigned int)u) << 16; return v.f;
}
__device__ __forceinline__ unsigned short f2bf(float f){
    union { float f; unsigned int i; } v; v.f = f;
    unsigned int r = v.i + 0x7fffu + ((v.i >> 16) & 1u);
    return (unsigned short)(r >> 16);
}
__device__ __forceinline__ void unpack8(uint4 v, float* f){
    f[0]=bf2f((unsigned short)(v.x & 0xffff)); f[1]=bf2f((unsigned short)(v.x>>16));
    f[2]=bf2f((unsigned short)(v.y & 0xffff)); f[3]=bf2f((unsigned short)(v.y>>16));
    f[4]=bf2f((unsigned short)(v.z & 0xffff)); f[5]=bf2f((unsigned short)(v.z>>16));
    f[6]=bf2f((unsigned short)(v.w & 0xffff)); f[7]=bf2f((unsigned short)(v.w>>16));
}
__device__ __forceinline__ void async_copy16(const void* g, void* l){
    __builtin_amdgcn_global_load_lds(
        (const __attribute__((address_space(1))) unsigned int*)g,
        (__attribute__((address_space(3))) unsigned int*)l, 16, 0, 0);
}
// xor-swizzled LDS granule index for 64c x 128t fp32 transpose tiles
// (granule = 4 floats along t; phys granule = c*32 + (g ^ (c&31)))
__device__ __forceinline__ int sgran(int c, int g){ return c*32 + (g ^ (c & 31)); }

// ---------------- rel MLP: rel[t][c] fp32 (once) ----------------
__global__ __launch_bounds__(256) void rel_kernel(const float* __restrict__ rw1,
    const float* __restrict__ rb1, const float* __restrict__ rw2,
    const float* __restrict__ rb2, float* __restrict__ rel)
{
    __shared__ float hsh[64];
    int t = blockIdx.x, c = threadIdx.x;
    int ty = t >> 4, tx = t & 15;
    if (c < 64){
        float y = ty*(1.0f/15.0f), xx = tx*(1.0f/15.0f);
        hsh[c] = fmaxf(y*rw1[2*c] + xx*rw1[2*c+1] + rb1[c], 0.0f);
    }
    __syncthreads();
    float acc = rb2[c];
    #pragma unroll 16
    for (int k = 0; k < 64; ++k) acc += hsh[k]*rw2[c*64 + k];
    rel[t*256 + c] = acc;
}

// ---------------- pos[w][t][c] = gp^T + rel  (vectorized swizzled transpose) ----------------
// grid: 64 w * 4 cq * 2 th = 512 blocks; 64 c x 128 t tile per block
__global__ __launch_bounds__(256) void posT_kernel(const float* __restrict__ gp,
    const float* __restrict__ rel, unsigned short* __restrict__ pos)
{
    __shared__ float tile[8192];
    const int w  = blockIdx.x >> 3;
    const int cq = (blockIdx.x >> 1) & 3, th = blockIdx.x & 1;
    const int c0 = cq << 6, t0 = th << 7, y0 = th << 3;
    const int wh = w >> 3, wwi = w & 7;
    const int tid = threadIdx.x;
    const float* gpb = gp + (size_t)c0*(HH*WW) + (size_t)(wh*16 + y0)*WW + wwi*16;
    #pragma unroll
    for (int i = 0; i < 8; ++i){
        int n = i*256 + tid, slot = n & 31, c = n >> 5;
        int yl = slot >> 2, xg = slot & 3;
        float4 v = *(const float4*)(gpb + (size_t)c*(HH*WW) + yl*WW + xg*4);
        *(float4*)&tile[sgran(c, slot)*4] = v;
    }
    __syncthreads();
    #pragma unroll
    for (int i = 0; i < 4; ++i){
        int n = i*256 + tid, j = n & 7, tl = n >> 3;
        int g = tl >> 2, e = tl & 3;
        const float* rl = rel + (t0 + tl)*256 + c0 + j*8;
        unsigned short o[8];
        #pragma unroll
        for (int m = 0; m < 8; ++m)
            o[m] = f2bf(tile[sgran(j*8 + m, g)*4 + e] + rl[m]);
        *(uint4*)&pos[((size_t)w*256 + t0 + tl)*CEMB + c0 + j*8] = *(uint4*)o;
    }
}

// ---------------- K2: window validity (max-pool > 0) ----------------
__global__ __launch_bounds__(256) void valid_kernel(const float* __restrict__ defe,
    float* __restrict__ validf, float* __restrict__ tail)
{
    __shared__ float red[4];
    int bw = blockIdx.x; int b = bw >> 6, w = bw & 63;
    int t = threadIdx.x; int ty = t >> 4, tx = t & 15;
    int wh = w >> 3, wwi = w & 7;
    float v = defe[(size_t)b*(HH*WW) + (wh*16+ty)*WW + wwi*16 + tx];
    int lane = t & 63, wave = t >> 6;
    for (int off = 1; off < 64; off <<= 1) v = fmaxf(v, __shfl_xor(v, off));
    if (lane == 0) red[wave] = v;
    __syncthreads();
    if (t == 0){
        float m = fmaxf(fmaxf(red[0], red[1]), fmaxf(red[2], red[3]));
        float r = (m > 0.0f) ? 1.0f : 0.0f;
        validf[bw] = r;
        tail[bw] = r;
    }
}

// ---------------- K3: window partition  backbone[B,C,H,W] -> x[b,w,t,c] bf16 ----------------
// grid: 256 bw * 4 cq * 2 th = 2048 blocks; 64 c x 128 t tile per block
__global__ __launch_bounds__(256) void partition_kernel(const float* __restrict__ bb,
    unsigned short* __restrict__ x)
{
    __shared__ float tile[8192];
    const int bw = blockIdx.x >> 3;
    const int b = bw >> 6, w = bw & 63;
    const int cq = (blockIdx.x >> 1) & 3, th = blockIdx.x & 1;
    const int c0 = cq << 6, t0 = th << 7, y0 = th << 3;
    const int wh = w >> 3, wwi = w & 7;
    const int tid = threadIdx.x;
    const float* bbb = bb + ((size_t)(b*CEMB + c0))*(HH*WW) + (size_t)(wh*16 + y0)*WW + wwi*16;
    #pragma unroll
    for (int i = 0; i < 8; ++i){
        int n = i*256 + tid, slot = n & 31, c = n >> 5;
        int yl = slot >> 2, xg = slot & 3;
        float4 v = *(const float4*)(bbb + (size_t)c*(HH*WW) + yl*WW + xg*4);
        *(float4*)&tile[sgran(c, slot)*4] = v;
    }
    __syncthreads();
    #pragma unroll
    for (int i = 0; i < 4; ++i){
        int n = i*256 + tid, j = n & 7, tl = n >> 3;
        int g = tl >> 2, e = tl & 3;
        unsigned short o[8];
        #pragma unroll
        for (int m = 0; m < 8; ++m)
            o[m] = f2bf(tile[sgran(j*8 + m, g)*4 + e]);
        *(uint4*)&x[((size_t)bw*256 + t0 + tl)*CEMB + c0 + j*8] = *(uint4*)o;
    }
}

// ---------------- weight fp32 -> bf16 ----------------
__global__ __launch_bounds__(256) void wcvt_kernel(const float* __restrict__ w,
    unsigned short* __restrict__ o, int n4)
{
    int i = blockIdx.x*256 + threadIdx.x;
    if (i < n4){
        float4 v = ((const float4*)w)[i];
        ushort4 u;
        u.x = f2bf(v.x); u.y = f2bf(v.y); u.z = f2bf(v.z); u.w = f2bf(v.w);
        ((ushort4*)o)[i] = u;
    }
}

// ---------------- xp = x + pos (bf16 elementwise, 8 el/thread) ----------------
__global__ __launch_bounds__(256) void addpos_kernel(const unsigned short* __restrict__ x,
    const unsigned short* __restrict__ pos, unsigned short* __restrict__ xp)
{
    size_t i = ((size_t)blockIdx.x*256 + threadIdx.x) * 8;
    size_t tok = i >> 8; int c = (int)(i & 255);
    size_t pi = ((tok & 16383) << 8) + c;
    uint4 xv = *(const uint4*)&x[i];
    uint4 pv = *(const uint4*)&pos[pi];
    float xf[8], pf[8]; unpack8(xv, xf); unpack8(pv, pf);
    unsigned short o[8];
    #pragma unroll
    for (int j = 0; j < 8; ++j) o[j] = f2bf(xf[j] + pf[j]);
    *(uint4*)&xp[i] = *(uint4*)o;
}

// ---------------- MFMA GEMM: out[M,N](bf16) = A[M,K](bf16) @ W[N,K]^T + bias ----------------
__global__ __launch_bounds__(256) void gemm_mfma(
    const unsigned short* __restrict__ A,
    const unsigned short* __restrict__ A2, int nsplit, int ldA,
    const unsigned short* __restrict__ W, int K,
    const float* __restrict__ bias,
    unsigned short* __restrict__ out, int ldO, int relu)
{
    __shared__ unsigned short As[128*32];
    __shared__ unsigned short Bs[128*32];
    const int m0 = blockIdx.x << 7, n0 = blockIdx.y << 7;
    const int tid = threadIdx.x;
    const int lane = tid & 63, wave = tid >> 6;
    const int wm = wave & 1, wn = wave >> 1;
    const int fl = lane & 15, quad = lane >> 4;

    const unsigned short* Ap = ((n0 < nsplit) ? A : A2) + (size_t)m0*ldA;
    const unsigned short* Wp = W + (size_t)n0*K;

    const int c0 = tid, c1 = tid + 256;
    const int r0 = c0 >> 2, o0 = (c0 & 3) << 3;
    const int r1 = c1 >> 2, o1 = (c1 & 3) << 3;

    f32x4 acc[4][4] = {};

    for (int k0 = 0; k0 < K; k0 += 32){
        async_copy16(Ap + (size_t)r0*ldA + k0 + o0, &As[c0 << 3]);
        async_copy16(Ap + (size_t)r1*ldA + k0 + o1, &As[c1 << 3]);
        async_copy16(Wp + (size_t)r0*K   + k0 + o0, &Bs[c0 << 3]);
        async_copy16(Wp + (size_t)r1*K   + k0 + o1, &Bs[c1 << 3]);
        __syncthreads();
        bf16x8 av[4], bv[4];
        #pragma unroll
        for (int i = 0; i < 4; ++i){
            av[i] = *(const bf16x8*)&As[(wm*64 + i*16 + fl)*32 + quad*8];
            bv[i] = *(const bf16x8*)&Bs[(wn*64 + i*16 + fl)*32 + quad*8];
        }
        #pragma unroll
        for (int i = 0; i < 4; ++i)
            #pragma unroll
            for (int j = 0; j < 4; ++j)
                acc[i][j] = __builtin_amdgcn_mfma_f32_16x16x32_bf16(av[i], bv[j], acc[i][j], 0, 0, 0);
        __syncthreads();
    }

    float bj[4];
    #pragma unroll
    for (int j = 0; j < 4; ++j) bj[j] = bias[n0 + wn*64 + j*16 + fl];
    #pragma unroll
    for (int i = 0; i < 4; ++i){
        int mrow = m0 + wm*64 + i*16 + quad*4;
        #pragma unroll
        for (int j = 0; j < 4; ++j){
            int col = n0 + wn*64 + j*16 + fl;
            #pragma unroll
            for (int r = 0; r < 4; ++r){
                float v = acc[i][j][r] + bj[j];
                if (relu) v = fmaxf(v, 0.0f);
                out[(size_t)(mrow + r)*ldO + col] = f2bf(v);
            }
        }
    }
}

// ---------------- MFMA GEMM + residual + LayerNorm (N == 256 exactly) ----------------
__global__ __launch_bounds__(256, 2) void gemm_ln(
    const unsigned short* __restrict__ A, int K,
    const unsigned short* __restrict__ W,
    const float* __restrict__ bias,
    const unsigned short* __restrict__ resid,
    const float* __restrict__ g, const float* __restrict__ b,
    unsigned short* __restrict__ out)
{
    __shared__ unsigned short As[128*32];
    __shared__ unsigned short Bs[256*32];
    __shared__ float psum[2][128];
    __shared__ float psq[2][128];
    const int m0 = blockIdx.x << 7;
    const int tid = threadIdx.x, lane = tid & 63, wave = tid >> 6;
    const int wm = wave & 1, wn = wave >> 1;
    const int fl = lane & 15, quad = lane >> 4;

    const unsigned short* Ap = A + (size_t)m0*K;

    f32x4 acc[4][8] = {};

    for (int k0 = 0; k0 < K; k0 += 32){
        {
            int c0 = tid, c1 = tid + 256;
            async_copy16(Ap + (size_t)(c0 >> 2)*K + k0 + ((c0 & 3) << 3), &As[c0 << 3]);
            async_copy16(Ap + (size_t)(c1 >> 2)*K + k0 + ((c1 & 3) << 3), &As[c1 << 3]);
        }
        #pragma unroll
        for (int t = 0; t < 4; ++t){
            int c = tid + t*256;
            async_copy16(W + (size_t)(c >> 2)*K + k0 + ((c & 3) << 3), &Bs[c << 3]);
        }
        __syncthreads();
        bf16x8 av[4], bv[8];
        #pragma unroll
        for (int i = 0; i < 4; ++i)
            av[i] = *(const bf16x8*)&As[(wm*64 + i*16 + fl)*32 + quad*8];
        #pragma unroll
        for (int j = 0; j < 8; ++j)
            bv[j] = *(const bf16x8*)&Bs[(wn*128 + j*16 + fl)*32 + quad*8];
        #pragma unroll
        for (int i = 0; i < 4; ++i)
            #pragma unroll
            for (int j = 0; j < 8; ++j)
                acc[i][j] = __builtin_amdgcn_mfma_f32_16x16x32_bf16(av[i], bv[j], acc[i][j], 0, 0, 0);
        __syncthreads();
    }

    float bcol[8], gcol[8], bbcol[8];
    #pragma unroll
    for (int j = 0; j < 8; ++j){
        int col = wn*128 + j*16 + fl;
        bcol[j] = bias[col]; gcol[j] = g[col]; bbcol[j] = b[col];
    }
    float s[4][4] = {{0}}, sq[4][4] = {{0}};
    #pragma unroll
    for (int i = 0; i < 4; ++i)
        #pragma unroll
        for (int r = 0; r < 4; ++r){
            int row = m0 + wm*64 + i*16 + quad*4 + r;
            #pragma unroll
            for (int j = 0; j < 8; ++j){
                float h = acc[i][j][r] + bcol[j]
                        + bf2f(resid[(size_t)row*256 + wn*128 + j*16 + fl]);
                acc[i][j][r] = h;
                s[i][r] += h; sq[i][r] += h*h;
            }
        }
    #pragma unroll
    for (int i = 0; i < 4; ++i)
        #pragma unroll
        for (int r = 0; r < 4; ++r){
            float ss = s[i][r], qq = sq[i][r];
            ss += __shfl_xor(ss, 1); qq += __shfl_xor(qq, 1);
            ss += __shfl_xor(ss, 2); qq += __shfl_xor(qq, 2);
            ss += __shfl_xor(ss, 4); qq += __shfl_xor(qq, 4);
            ss += __shfl_xor(ss, 8); qq += __shfl_xor(qq, 8);
            if (fl == 0){
                int lr = wm*64 + i*16 + quad*4 + r;
                psum[wn][lr] = ss; psq[wn][lr] = qq;
            }
        }
    __syncthreads();
    #pragma unroll
    for (int i = 0; i < 4; ++i)
        #pragma unroll
        for (int r = 0; r < 4; ++r){
            int lr = wm*64 + i*16 + quad*4 + r;
            float mu  = (psum[0][lr] + psum[1][lr]) * (1.0f/256.0f);
            float var = (psq[0][lr] + psq[1][lr]) * (1.0f/256.0f) - mu*mu;
            float rstd = rsqrtf(var + 1e-5f);
            #pragma unroll
            for (int j = 0; j < 8; ++j){
                int col = wn*128 + j*16 + fl;
                out[(size_t)(m0 + lr)*256 + col] =
                    f2bf((acc[i][j][r] - mu)*rstd*gcol[j] + bbcol[j]);
            }
        }
}

// ---------------- MFMA flash attention ----------------
template<int L, bool CROSS>
__global__ __launch_bounds__(256) void attn_mfma(const unsigned short* __restrict__ qkv,
    unsigned short* __restrict__ attn_out, const float* __restrict__ validf)
{
    constexpr int QW  = (L == 256) ? 64 : 16;
    constexpr int MI  = QW / 16;
    constexpr int VTS = L + 8;
    constexpr int LOG = (L == 256) ? 8 : 6;
    __shared__ unsigned short Ks[L*32];
    __shared__ unsigned short Vt[32*VTS];
    __shared__ unsigned short Ps[4*QW*72];

    const int s = blockIdx.x, h = blockIdx.y;
    int base, stride;
    if (CROSS){ base = (s >> 8)*16384 + (s & 255); stride = 256; }
    else      { base = s << 8; stride = 1; }
    const int tid = threadIdx.x, lane = tid & 63, wave = tid >> 6;
    const int fl = lane & 15, quad = lane >> 4;
    const float scale = 0.17677669529663687f;

    for (int cid = tid; cid < L*4; cid += 256){
        int j = cid >> 2, part = cid & 3;
        async_copy16(qkv + (size_t)(base + j*stride)*768 + 256 + h*32 + part*8, &Ks[cid*8]);
    }
    for (int e = tid; e < L*4; e += 256){
        int j = e & (L-1), dp = e >> LOG;
        uint4 vv = *(const uint4*)(qkv + (size_t)(base + j*stride)*768 + 512 + h*32 + dp*8);
        unsigned short tmp[8]; *(uint4*)tmp = vv;
        #pragma unroll
        for (int d = 0; d < 8; ++d) Vt[(dp*8 + d)*VTS + j] = tmp[d];
    }
    __syncthreads();

    bf16x8 qf[MI];
    #pragma unroll
    for (int mi = 0; mi < MI; ++mi){
        int q = wave*QW + mi*16 + fl;
        qf[mi] = *(const bf16x8*)(qkv + (size_t)(base + q*stride)*768 + h*32 + quad*8);
    }
    float vm[4];
    if (CROSS){
        #pragma unroll
        for (int nj = 0; nj < 4; ++nj) vm[nj] = validf[(s >> 8)*64 + nj*16 + fl];
    }

    f32x4 oacc[MI][2] = {};
    float lpart[MI][4] = {};
    unsigned short* Pw = &Ps[wave*QW*72];

    for (int j0 = 0; j0 < L; j0 += 64){
        bf16x8 kf[4];
        #pragma unroll
        for (int nj = 0; nj < 4; ++nj)
            kf[nj] = *(const bf16x8*)&Ks[(j0 + nj*16 + fl)*32 + quad*8];
        f32x4 sacc[MI][4] = {};
        #pragma unroll
        for (int mi = 0; mi < MI; ++mi)
            #pragma unroll
            for (int nj = 0; nj < 4; ++nj)
                sacc[mi][nj] = __builtin_amdgcn_mfma_f32_16x16x32_bf16(qf[mi], kf[nj], sacc[mi][nj], 0, 0, 0);
        #pragma unroll
        for (int mi = 0; mi < MI; ++mi)
            #pragma unroll
            for (int nj = 0; nj < 4; ++nj)
                #pragma unroll
                for (int r = 0; r < 4; ++r){
                    float p = __expf(sacc[mi][nj][r] * scale);
                    if (CROSS) p *= vm[nj];
                    lpart[mi][r] += p;
                    Pw[(mi*16 + quad*4 + r)*72 + nj*16 + fl] = f2bf(p);
                }
        #pragma unroll
        for (int kk = 0; kk < 2; ++kk){
            bf16x8 vf[2];
            #pragma unroll
            for (int nd = 0; nd < 2; ++nd)
                vf[nd] = *(const bf16x8*)&Vt[(nd*16 + fl)*VTS + j0 + kk*32 + quad*8];
            #pragma unroll
            for (int mi = 0; mi < MI; ++mi){
                bf16x8 pf = *(const bf16x8*)&Pw[(mi*16 + fl)*72 + kk*32 + quad*8];
                #pragma unroll
                for (int nd = 0; nd < 2; ++nd)
                    oacc[mi][nd] = __builtin_amdgcn_mfma_f32_16x16x32_bf16(pf, vf[nd], oacc[mi][nd], 0, 0, 0);
            }
        }
    }

    #pragma unroll
    for (int mi = 0; mi < MI; ++mi)
        #pragma unroll
        for (int r = 0; r < 4; ++r){
            float l = lpart[mi][r];
            l += __shfl_xor(l, 1); l += __shfl_xor(l, 2);
            l += __shfl_xor(l, 4); l += __shfl_xor(l, 8);
            lpart[mi][r] = 1.0f / l;
        }
    #pragma unroll
    for (int mi = 0; mi < MI; ++mi)
        #pragma unroll
        for (int nd = 0; nd < 2; ++nd)
            #pragma unroll
            for (int r = 0; r < 4; ++r){
                int q = wave*QW + mi*16 + quad*4 + r;
                attn_out[(size_t)(base + q*stride)*CEMB + h*32 + nd*16 + fl] =
                    f2bf(oacc[mi][nd][r] * lpart[mi][r]);
            }
}

// ---------------- final scatter: out = backbone + valid * x (vectorized swizzled) ----------------
// grid: 256 bw * 4 cq * 2 th = 2048 blocks; 64 c x 128 t tile per block
__global__ __launch_bounds__(256) void scatter_kernel(const float* __restrict__ bb,
    const unsigned short* __restrict__ x, const float* __restrict__ validf,
    float* __restrict__ out)
{
    __shared__ float tile[8192];
    const int bw = blockIdx.x >> 3;
    const int b = bw >> 6, w = bw & 63;
    const int cq = (blockIdx.x >> 1) & 3, th = blockIdx.x & 1;
    const int c0 = cq << 6, t0 = th << 7, y0 = th << 3;
    const int wh = w >> 3, wwi = w & 7;
    const int tid = threadIdx.x;
    const float vf = validf[bw];
    // phase 1: x (t-major bf16) -> swizzled LDS (c-major fp32)
    #pragma unroll
    for (int i = 0; i < 4; ++i){
        int n = i*256 + tid, j = n & 7, tl = n >> 3;
        int g = tl >> 2, e = tl & 3;
        uint4 xv = *(const uint4*)&x[((size_t)bw*256 + t0 + tl)*CEMB + c0 + j*8];
        float f[8]; unpack8(xv, f);
        #pragma unroll
        for (int m = 0; m < 8; ++m)
            tile[sgran(j*8 + m, g)*4 + e] = f[m];
    }
    __syncthreads();
    // phase 2: out = bb + vf * tile (c-major float4)
    const size_t gbase = ((size_t)(b*CEMB + c0))*(HH*WW) + (size_t)(wh*16 + y0)*WW + wwi*16;
    #pragma unroll
    for (int i = 0; i < 8; ++i){
        int n = i*256 + tid, slot = n & 31, c = n >> 5;
        int yl = slot >> 2, xg = slot & 3;
        size_t gi = gbase + (size_t)c*(HH*WW) + yl*WW + xg*4;
        float4 bv = *(const float4*)(bb + gi);
        float4 xv = *(const float4*)&tile[sgran(c, slot)*4];
        float4 ov;
        ov.x = bv.x + vf*xv.x; ov.y = bv.y + vf*xv.y;
        ov.z = bv.z + vf*xv.z; ov.w = bv.w + vf*xv.w;
        *(float4*)(out + gi) = ov;
    }
}

extern "C" void kernel_launch(void* const* d_in, const int* in_sizes, int n_in,
                              void* d_out, int out_size, void* d_ws, size_t ws_size,
                              hipStream_t stream)
{
    (void)in_sizes; (void)n_in; (void)out_size; (void)ws_size;
    const float* backbone = (const float*)d_in[0];
    const float* defe     = (const float*)d_in[1];
    const float* gpe      = (const float*)d_in[3];
    const float* rw1 = (const float*)d_in[4];
    const float* rb1 = (const float*)d_in[5];
    const float* rw2 = (const float*)d_in[6];
    const float* rb2 = (const float*)d_in[7];
    const float* ipw = (const float*)d_in[8];
    const float* ipb = (const float*)d_in[9];
    const float* opw = (const float*)d_in[10];
    const float* opb = (const float*)d_in[11];
    const float* l1w = (const float*)d_in[12];
    const float* l1b = (const float*)d_in[13];
    const float* l2w = (const float*)d_in[14];
    const float* l2b = (const float*)d_in[15];
    const float* g1  = (const float*)d_in[16];
    const float* b1  = (const float*)d_in[17];
    const float* g2  = (const float*)d_in[18];
    const float* b2  = (const float*)d_in[19];

    char* ws = (char*)d_ws;
    unsigned short* pos    = (unsigned short*)(ws);               //   8,388,608
    unsigned short* x      = (unsigned short*)(ws +   8388608);   //  33,554,432
    unsigned short* qkv    = (unsigned short*)(ws +  41943040);   // 100,663,296 (later: src + ff)
    unsigned short* shared_= (unsigned short*)(ws + 142606336);   //  33,554,432 (xp -> attn)
    float*          validf = (float*)(ws + 176160768);            //       1,024
    unsigned short* ipw16  = (unsigned short*)(ws + 176161792);
    unsigned short* opw16  = (unsigned short*)(ws + 176555008);
    unsigned short* l1w16  = (unsigned short*)(ws + 176686080);
    unsigned short* l2w16  = (unsigned short*)(ws + 177210368);
    float*          rel    = (float*)(ws + 177734656);
    unsigned short* src = qkv;
    unsigned short* ff  = qkv + 16777216;
    float* outf = (float*)d_out;

    wcvt_kernel<<<192, 256, 0, stream>>>(ipw, ipw16, 49152);
    wcvt_kernel<<< 64, 256, 0, stream>>>(opw, opw16, 16384);
    wcvt_kernel<<<256, 256, 0, stream>>>(l1w, l1w16, 65536);
    wcvt_kernel<<<256, 256, 0, stream>>>(l2w, l2w16, 65536);
    rel_kernel<<<256, 256, 0, stream>>>(rw1, rb1, rw2, rb2, rel);
    posT_kernel<<<512, 256, 0, stream>>>(gpe, rel, pos);
    valid_kernel<<<BB*NW, 256, 0, stream>>>(defe, validf, outf + (size_t)BB*CEMB*HH*WW);
    partition_kernel<<<2048, 256, 0, stream>>>(backbone, x);

    for (int layer = 0; layer < 2; ++layer){
        addpos_kernel<<<8192, 256, 0, stream>>>(x, pos, shared_);
        gemm_mfma<<<dim3(512, 6), 256, 0, stream>>>(shared_, x, 512, CEMB, ipw16, CEMB, ipb, qkv, 768, 0);
        if (layer == 0)
            attn_mfma<256, false><<<dim3(BB*NW, NHEAD), 256, 0, stream>>>(qkv, shared_, validf);
        else
            attn_mfma<64, true><<<dim3(BB*TT, NHEAD), 256, 0, stream>>>(qkv, shared_, validf);
        gemm_ln<<<dim3(512, 1), 256, 0, stream>>>(shared_, CEMB, opw16, opb, x, g1, b1, src);
        for (int ch = 0; ch < 2; ++ch){
            const int BIG = 1 << 30;
            unsigned short* srcC = src + (size_t)ch*8388608;
            gemm_mfma<<<dim3(256, 8), 256, 0, stream>>>(srcC, srcC, BIG, CEMB, l1w16, CEMB, l1b, ff, DFF, 1);
            gemm_ln<<<dim3(256, 1), 256, 0, stream>>>(ff, DFF, l2w16, l2b, srcC, g2, b2,
                                                      x + (size_t)ch*8388608);
        }
    }
    scatter_kernel<<<2048, 256, 0, stream>>>(backbone, x, validf, outf);
}